// Round 2
// 521.020 us; speedup vs baseline: 1.0895x; 1.0895x over previous
//
#include <hip/hip_runtime.h>
#include <math.h>

#define BB 8
#define MTOK 768
#define NTOK 128
#define LTOK 64
#define TT 960          // MTOK+NTOK+LTOK
#define BT 7680         // BB*TT
#define DD 256
#define HH 8
#define HD 32
#define KNN 32
#define FFD 1024
#define NLAYERS 4
#define SCALE_ATT 0.17677669529663687f  // 1/sqrt(32)

typedef __attribute__((ext_vector_type(8))) short bfrag_t;   // 8 bf16 (4 VGPRs)
typedef __attribute__((ext_vector_type(4))) float accfrag_t; // 4 fp32 acc

__device__ __forceinline__ float b2f(unsigned short u) {
  union { unsigned int i; float f; } c; c.i = ((unsigned int)u) << 16; return c.f;
}
__device__ __forceinline__ unsigned short f2b(float f) {
  union { float f; unsigned int i; } c; c.f = f;
  return (unsigned short)((c.i + 0x7fffu + ((c.i >> 16) & 1u)) >> 16);
}
__device__ __forceinline__ float load_elem(const void* p, size_t i, int f) {
  return f ? b2f(((const unsigned short*)p)[i]) : ((const float*)p)[i];
}
// fragment-packed layout: element (row,k[col]) of [R x K] ->
//   ((row/16)*NKS + k/32)*512 + (((k>>3)&3)*16 + row%16)*8 + k%8
__device__ __forceinline__ size_t pk_addr(int row, int col, int nks) {
  return ((size_t)((row >> 4) * nks + (col >> 5)) << 9)
       + (size_t)(((((col >> 3) & 3) << 4) + (row & 15)) * 8 + (col & 7));
}
__device__ __forceinline__ uint4 pack8(const float* v) {
  uint4 u;
  u.x = (unsigned)f2b(v[0]) | ((unsigned)f2b(v[1]) << 16);
  u.y = (unsigned)f2b(v[2]) | ((unsigned)f2b(v[3]) << 16);
  u.z = (unsigned)f2b(v[4]) | ((unsigned)f2b(v[5]) << 16);
  u.w = (unsigned)f2b(v[6]) | ((unsigned)f2b(v[7]) << 16);
  return u;
}
// scene->XCD swizzle
__device__ __forceinline__ int swiz_m0(int blk)  { return (blk & 7) * TT + (blk >> 3) * 32; }
__device__ __forceinline__ int swiz_tok(int blk) { return (blk & 7) * TT + (blk >> 3); }

// ---------------- dtype detector ----------------
__global__ __launch_bounds__(256)
void detect_kernel(const void* tok, int* flag) {
  __shared__ int cnt;
  if (threadIdx.x == 0) cnt = 0;
  __syncthreads();
  const unsigned short* u = (const unsigned short*)tok;
  int ok = 0;
  for (int i = threadIdx.x; i < 1024; i += 256) {
    int e = (u[i] >> 7) & 0xFF;
    if (e >= 100 && e <= 140) ok++;
  }
  atomicAdd(&cnt, ok);
  __syncthreads();
  if (threadIdx.x == 0) *flag = (cnt >= 922) ? 1 : 0;
}

// ---------------- positions + params -> fp32 ----------------
#define FB_BQ 0
#define FB_BK 1024
#define FB_BV 2048
#define FB_BO 3072
#define FB_B1 4096
#define FB_B2 8192
#define FB_LN1S 9216
#define FB_LN1B 10240
#define FB_LN2S 11264
#define FB_LN2B 12288
#define FB_TOTAL 13312
struct ParamSrc { const void* p[13]; };
__global__ __launch_bounds__(256)
void conv_misc_kernel(ParamSrc ps, const int* flag, float* __restrict__ dst,
                      float* __restrict__ posf) {
  int f = *flag;
  if (blockIdx.x < BB) {
    int b = blockIdx.x;
    for (int t = threadIdx.x; t < TT * 2; t += 256) {
      int tok = t >> 1, c = t & 1;
      const void* p; size_t idx;
      if (tok < MTOK)             { p = ps.p[10]; idx = (size_t)(b * MTOK + tok) * 2 + c; }
      else if (tok < MTOK + NTOK) { p = ps.p[11]; idx = (size_t)(b * NTOK + tok - MTOK) * 2 + c; }
      else                        { p = ps.p[12]; idx = (size_t)(b * LTOK + tok - MTOK - NTOK) * 2 + c; }
      posf[((size_t)b * TT + tok) * 2 + c] = load_elem(p, idx, f);
    }
    return;
  }
  int i = (blockIdx.x - BB) * 256 + threadIdx.x;
  if (i >= FB_TOTAL) return;
  int src; size_t off;
  if (i < 4096)      { src = i >> 10;              off = i & 1023; }
  else if (i < 8192) { src = 4;                    off = i - 4096; }
  else               { src = 5 + ((i - 8192) >> 10); off = (i - 8192) & 1023; }
  dst[i] = load_elem(ps.p[src], off, f);
}

// ---------------- pack all weights into fragment order ----------------
struct PackSrc { const void* s[6]; };
__global__ __launch_bounds__(256)
void packW_kernel(PackSrc w, const int* flag,
                  unsigned short* __restrict__ Wqkvpk, unsigned short* __restrict__ Wopk,
                  unsigned short* __restrict__ W1pk, unsigned short* __restrict__ W2pk) {
  int f = *flag;
  int id = blockIdx.x * 256 + threadIdx.x;
  const void* src; unsigned short* dst; int layer, e, K, N;
  if (id < 786432) {                    // Wq,Wk,Wv: 4 layers x 3 x 65536
    layer = id / 196608; int rest = id % 196608; int sel = rest / 65536; e = rest % 65536;
    src = w.s[sel]; dst = Wqkvpk + id; K = 256; N = 256;
  } else if (id < 1048576) {            // Wo
    int off = id - 786432; layer = off / 65536; e = off % 65536;
    src = w.s[3]; dst = Wopk + off; K = 256; N = 256;
  } else if (id < 2097152) {            // W1
    int off = id - 1048576; layer = off / 262144; e = off % 262144;
    src = w.s[4]; dst = W1pk + off; K = 256; N = 1024;
  } else {                              // W2
    int off = id - 2097152; layer = off / 262144; e = off % 262144;
    src = w.s[5]; dst = W2pk + off; K = 1024; N = 256;
  }
  int nks = K >> 5;
  int cb = e / (nks * 512);
  int ks = (e / 512) % nks;
  int lane = (e >> 3) & 63, j = e & 7;
  int col = cb * 16 + (lane & 15);
  int k = ks * 32 + (lane >> 4) * 8 + j;
  size_t si = (size_t)layer * K * N + (size_t)k * N + col;
  *dst = f ? ((const unsigned short*)src)[si] : f2b(((const float*)src)[si]);
}

// ---------------- prep: positional embedding + stream init ----------------
__global__ __launch_bounds__(256)
void prep_kernel(const void* mt, const void* at, const void* lt,
                 const float* __restrict__ posf, const int* flag,
                 unsigned short* __restrict__ pe_b, float* __restrict__ out_f,
                 unsigned short* __restrict__ pk1, unsigned short* __restrict__ qkpk) {
  int n = swiz_tok(blockIdx.x), d = threadIdx.x;
  int b = n / TT, t = n - b * TT;
  int f = *flag;
  const void* src; size_t si;
  if (t < MTOK)              { src = mt; si = (size_t)(b * MTOK + t) * DD + d; }
  else if (t < MTOK + NTOK)  { src = at; si = (size_t)(b * NTOK + (t - MTOK)) * DD + d; }
  else                       { src = lt; si = (size_t)(b * LTOK + (t - MTOK - NTOK)) * DD + d; }
  float x = load_elem(src, si, f);
  float px = posf[((size_t)b * TT + t) * 2 + 0];
  float py = posf[((size_t)b * TT + t) * 2 + 1];
  float coord = (d < 128) ? py : px;
  int j = d & 127;
  float expo = (float)(2 * (j >> 1)) / 128.0f;
  float dim_t = powf(10000.0f, expo);
  float e = coord * 6.283185307179586f / dim_t;
  float p = (j & 1) ? cosf(e) : sinf(e);
  size_t o = (size_t)n * DD + d;
  pe_b[o] = f2b(p);
  out_f[o] = x;
  size_t pa = pk_addr(n, d, 8);
  pk1[pa] = f2b(x);
  qkpk[pa] = f2b(x + p);
}

// ---------------- KNN: threshold-prune + bitonic top-32 (exact) ----------------
// u64 key = (d2_bits << 32) | local_idx  -> ascending order == (d2, idx) lex,
// which matches jax.lax.top_k(-d2) tie-breaking exactly.
__device__ __forceinline__ unsigned long long shfl_xor_u64(unsigned long long v, int m) {
  unsigned lo = (unsigned)v, hi = (unsigned)(v >> 32);
  lo = (unsigned)__shfl_xor((int)lo, m);
  hi = (unsigned)__shfl_xor((int)hi, m);
  return ((unsigned long long)hi << 32) | (unsigned long long)lo;
}
__device__ __forceinline__ unsigned long long shfl_u64(unsigned long long v, int srcLane) {
  unsigned lo = (unsigned)v, hi = (unsigned)(v >> 32);
  lo = (unsigned)__shfl((int)lo, srcLane);
  hi = (unsigned)__shfl((int)hi, srcLane);
  return ((unsigned long long)hi << 32) | (unsigned long long)lo;
}
// full 64-element cross-lane bitonic sort, ascending by lane id
__device__ __forceinline__ unsigned long long bitonic64(unsigned long long key, int lane) {
#pragma unroll
  for (int kk = 2; kk <= 64; kk <<= 1) {
#pragma unroll
    for (int j = kk >> 1; j > 0; j >>= 1) {
      unsigned long long other = shfl_xor_u64(key, j);
      bool small_ = (lane & j) == 0;
      bool dir = (lane & kk) == 0;
      bool keep = ((key < other) == (small_ == dir));
      key = keep ? key : other;
    }
  }
  return key;
}

__global__ __launch_bounds__(256)
void knn_kernel(const float* __restrict__ posf, int* __restrict__ idx_out) {
  __shared__ float sx[TT], sy[TT];
  __shared__ unsigned long long cbuf[4][64];
  int b = blockIdx.x & 7;
  int qbase = (blockIdx.x >> 3) * 4;
  for (int t = threadIdx.x; t < TT; t += 256) {
    sx[t] = posf[((size_t)b * TT + t) * 2 + 0];
    sy[t] = posf[((size_t)b * TT + t) * 2 + 1];
  }
  __syncthreads();
  int wave = threadIdx.x >> 6, lane = threadIdx.x & 63;
  int t = qbase + wave;
  float qx = sx[t], qy = sy[t];

  // 15 keys per lane covering all 960 points
  unsigned long long k[15];
#pragma unroll
  for (int c = 0; c < 15; c++) {
    int j = c * 64 + lane;
    float dx = qx - sx[j], dy = qy - sy[j];
    float d2 = __fadd_rn(__fmul_rn(dx, dx), __fmul_rn(dy, dy));
    k[c] = ((unsigned long long)__float_as_uint(d2) << 32) | (unsigned)j;
  }

  // per-lane min (tree)
  unsigned long long lm = k[0];
#pragma unroll
  for (int c = 1; c < 15; c++) lm = (k[c] < lm) ? k[c] : lm;

  // sort 64 lane-mins; the 32nd smallest is a provable upper bound on the
  // 32nd smallest key overall (32 distinct lanes each own a key <= it).
  unsigned long long sm = bitonic64(lm, lane);
  unsigned long long thr = shfl_u64(sm, 31);   // broadcast sorted[31]

  // count candidates <= thr, exclusive scan across wave
  int c_l = 0;
#pragma unroll
  for (int c = 0; c < 15; c++) c_l += (k[c] <= thr) ? 1 : 0;
  int inc = c_l;
#pragma unroll
  for (int o = 1; o < 64; o <<= 1) {
    int tt = __shfl_up(inc, o);
    inc += (lane >= o) ? tt : 0;
  }
  int total = __shfl(inc, 63);
  int pos = inc - c_l;

  if (total <= 64) {
    // compact candidates into per-wave LDS slots (one per lane), sort, emit
    unsigned long long* wb = cbuf[wave];
#pragma unroll
    for (int c = 0; c < 15; c++) {
      if (k[c] <= thr) { wb[pos] = k[c]; pos++; }
    }
    unsigned long long cand = (lane < total) ? wb[lane] : ~0ull;
    cand = bitonic64(cand, lane);
    if (lane < KNN)
      idx_out[((size_t)(b * TT + t)) * KNN + lane] = b * TT + (int)(cand & 0xFFFFFFFFu);
  } else {
    // rare exact fallback: 32x tournament extraction on u64 keys
    unsigned res = 0;
    for (int i = 0; i < KNN; i++) {
      unsigned long long m = k[0];
#pragma unroll
      for (int c = 1; c < 15; c++) m = (k[c] < m) ? k[c] : m;
#pragma unroll
      for (int o = 32; o > 0; o >>= 1) {
        unsigned long long om = shfl_xor_u64(m, o);
        m = (om < m) ? om : m;
      }
      if (lane == i) res = (unsigned)(m & 0xFFFFFFFFu);
      int owner = (int)(m & 63u), ch = (int)(((unsigned)(m & 0xFFFFFFFFu)) >> 6);
      if (lane == owner) {
#pragma unroll
        for (int c = 0; c < 15; c++) if (c == ch) k[c] = ~0ull;
      }
    }
    if (lane < KNN)
      idx_out[((size_t)(b * TT + t)) * KNN + lane] = b * TT + (int)res;
  }
}

// ---------------- wave GEMM: 16 rows x 64 cols, packed operands, no LDS ----------------
// FIX (R11 bug): block strides are NKS*512 shorts (512 per 32-k slice), not NKS*64.
template<int NKS>
__device__ __forceinline__ void wavegemm(const unsigned short* __restrict__ Apk,
                                         const unsigned short* __restrict__ Bpk,
                                         int rb, int cb0, accfrag_t (&acc)[4]) {
  const int lane = threadIdx.x & 63;
  accfrag_t z = {0.f, 0.f, 0.f, 0.f};
#pragma unroll
  for (int nt = 0; nt < 4; nt++) acc[nt] = z;
  const unsigned short* ap = Apk + ((size_t)rb * NKS * 512 + lane * 8);
  const unsigned short* bp = Bpk + ((size_t)cb0 * NKS * 512 + lane * 8);
#pragma unroll 4
  for (int ks = 0; ks < NKS; ks++) {
    bfrag_t a = *(const bfrag_t*)(ap + ks * 512);
#pragma unroll
    for (int nt = 0; nt < 4; nt++) {
      bfrag_t b = *(const bfrag_t*)(bp + (size_t)(nt * NKS + ks) * 512);
      acc[nt] = __builtin_amdgcn_mfma_f32_16x16x32_bf16(a, b, acc[nt], 0, 0, 0);
    }
  }
}

// ---------------- QKV GEMM: grid 1440 (8 scenes x 15 rbg x 12 cg), 4 waves/block ----------------
__global__ __launch_bounds__(256)
void qkv_kernel(const unsigned short* __restrict__ qkpk,
                const unsigned short* __restrict__ outpk,
                const unsigned short* __restrict__ Wl,
                const float* __restrict__ pb, int l,
                unsigned short* __restrict__ QKV) {
  int scene = blockIdx.x & 7, r = blockIdx.x >> 3;
  int rbg = r % 15, cgall = r / 15;           // cgall 0..11
  int wave = threadIdx.x >> 6, lane = threadIdx.x & 63;
  int rb = scene * 60 + rbg * 4 + wave;
  int sel = cgall >> 2, cg = cgall & 3;
  const unsigned short* A = (sel < 2) ? qkpk : outpk;
  const unsigned short* B = Wl + sel * 65536;
  const float* bias = pb + sel * 1024 + l * 256;
  accfrag_t acc[4];
  wavegemm<8>(A, B, rb, cg * 4, acc);
  int l16 = lane & 15, lq = lane >> 4;
  unsigned short* C = QKV + (size_t)sel * BT * DD;
#pragma unroll
  for (int nt = 0; nt < 4; nt++) {
    int col = cg * 64 + nt * 16 + l16;
    float bv = bias[col];
#pragma unroll
    for (int r4 = 0; r4 < 4; r4++) {
      int row = rb * 16 + lq * 4 + r4;
      C[(size_t)row * DD + col] = f2b(acc[nt][r4] + bv);
    }
  }
}

// ---------------- attention (packed output) ----------------
__global__ __launch_bounds__(256)
void attn_kernel(const unsigned short* __restrict__ QKV,
                 const int* __restrict__ idx,
                 unsigned short* __restrict__ attnpk) {
  __shared__ unsigned short kn[KNN][DD + 8];
  __shared__ unsigned short vn[KNN][DD + 8];
  __shared__ float qs[DD];
  __shared__ float att[HH][KNN];
  __shared__ int nb[KNN];
  const unsigned short* Q = QKV;
  const unsigned short* K = QKV + (size_t)BT * DD;
  const unsigned short* V = QKV + 2 * (size_t)BT * DD;
  int n = swiz_tok(blockIdx.x), tid = threadIdx.x;
  if (tid < KNN) nb[tid] = idx[n * KNN + tid];
  qs[tid] = b2f(Q[(size_t)n * DD + tid]);
  __syncthreads();
#pragma unroll
  for (int p = 0; p < 4; p++) {
    int e = p * 256 + tid;
    int r = e >> 5, c8 = (e & 31) * 8;
    int srow = nb[r];
    *(uint4*)(&kn[r][c8]) = *(const uint4*)(K + (size_t)srow * DD + c8);
    *(uint4*)(&vn[r][c8]) = *(const uint4*)(V + (size_t)srow * DD + c8);
  }
  __syncthreads();
  int h = tid >> 5, kk = tid & 31;
  float dot = 0.0f;
#pragma unroll
  for (int d = 0; d < HD; d++) dot += qs[h * HD + d] * b2f(kn[kk][h * HD + d]);
  float sc = dot * SCALE_ATT;
  float mx = sc;
#pragma unroll
  for (int o = 16; o > 0; o >>= 1) mx = fmaxf(mx, __shfl_xor(mx, o, 32));
  float ex = expf(sc - mx);
  float sm = ex;
#pragma unroll
  for (int o = 16; o > 0; o >>= 1) sm += __shfl_xor(sm, o, 32);
  att[h][kk] = ex / sm;
  __syncthreads();
  int d = kk;
  float oacc = 0.0f;
#pragma unroll
  for (int k2 = 0; k2 < KNN; k2++) oacc += att[h][k2] * b2f(vn[k2][h * HD + d]);
  attnpk[pk_addr(n, tid, 8)] = f2b(oacc);
}

// ---------------- Wo GEMM + bias + resid -> sbuf (f32) ----------------
__global__ __launch_bounds__(256)
void wo_kernel(const unsigned short* __restrict__ attnpk,
               const unsigned short* __restrict__ Wl,
               const float* __restrict__ bo,
               const float* __restrict__ out_f,
               float* __restrict__ sbuf) {
  int scene = blockIdx.x & 7, r = blockIdx.x >> 3;     // grid 480
  int rbg = r % 15, cg = r / 15;                       // cg 0..3
  int wave = threadIdx.x >> 6, lane = threadIdx.x & 63;
  int rb = scene * 60 + rbg * 4 + wave;
  accfrag_t acc[4];
  wavegemm<8>(attnpk, Wl, rb, cg * 4, acc);
  int l16 = lane & 15, lq = lane >> 4;
#pragma unroll
  for (int nt = 0; nt < 4; nt++) {
    int col = cg * 64 + nt * 16 + l16;
    float bv = bo[col];
#pragma unroll
    for (int r4 = 0; r4 < 4; r4++) {
      int row = rb * 16 + lq * 4 + r4;
      sbuf[(size_t)row * DD + col] = acc[nt][r4] + bv + out_f[(size_t)row * DD + col];
    }
  }
}

// ---------------- LN1: sbuf -> yf(=out_f, f32 rm) + xpk(=pk1, packed bf16) ----------------
__global__ __launch_bounds__(256)
void ln1_kernel(const float* __restrict__ sbuf, float* __restrict__ yf,
                unsigned short* __restrict__ xpk,
                const float* __restrict__ g, const float* __restrict__ bta) {
  int m0 = swiz_m0(blockIdx.x);                        // grid 240
  int row = m0 + (threadIdx.x >> 3), sub = threadIdx.x & 7;
  const float* src = sbuf + (size_t)row * DD + sub * 32;
  float v[32]; float s = 0.f, s2 = 0.f;
#pragma unroll
  for (int i = 0; i < 8; i++) {
    float4 t = *(const float4*)(src + i * 4);
    v[i*4+0]=t.x; v[i*4+1]=t.y; v[i*4+2]=t.z; v[i*4+3]=t.w;
    s += t.x + t.y + t.z + t.w;
    s2 += t.x*t.x + t.y*t.y + t.z*t.z + t.w*t.w;
  }
#pragma unroll
  for (int o = 1; o < 8; o <<= 1) { s += __shfl_xor(s, o); s2 += __shfl_xor(s2, o); }
  float mu = s * (1.0f/256.0f);
  float var = s2 * (1.0f/256.0f) - mu * mu;
  float rstd = 1.0f / sqrtf(fmaxf(var, 0.f) + 1e-5f);
  int c0 = sub * 32;
#pragma unroll
  for (int i = 0; i < 32; i++) v[i] = (v[i] - mu) * rstd * g[c0+i] + bta[c0+i];
  float* yo = yf + (size_t)row * DD + c0;
#pragma unroll
  for (int i = 0; i < 8; i++)
    *(float4*)(yo + i*4) = make_float4(v[i*4], v[i*4+1], v[i*4+2], v[i*4+3]);
  unsigned short* xp = xpk + (((size_t)(row >> 4) * 8 + sub) << 9) + (size_t)(row & 15) * 8;
#pragma unroll
  for (int lqc = 0; lqc < 4; lqc++)
    *(uint4*)(xp + lqc * 128) = pack8(&v[lqc * 8]);
}

// ---------------- FFN1: xpk @ W1 + b1, ReLU -> hpk (packed) ----------------
__global__ __launch_bounds__(256)
void ffn1_kernel(const unsigned short* __restrict__ xpk,
                 const unsigned short* __restrict__ Wl,
                 const float* __restrict__ b1,
                 unsigned short* __restrict__ hpk) {
  int scene = blockIdx.x & 7, r = blockIdx.x >> 3;     // grid 1920
  int rbg = r % 15, cg = r / 15;                       // cg 0..15
  int wave = threadIdx.x >> 6, lane = threadIdx.x & 63;
  int rb = scene * 60 + rbg * 4 + wave;
  accfrag_t acc[4];
  wavegemm<8>(xpk, Wl, rb, cg * 4, acc);
  int l16 = lane & 15, lq = lane >> 4;
#pragma unroll
  for (int nt = 0; nt < 4; nt++) {
    int col = cg * 64 + nt * 16 + l16;
    float bv = b1[col];
#pragma unroll
    for (int r4 = 0; r4 < 4; r4++) {
      int row = rb * 16 + lq * 4 + r4;
      hpk[pk_addr(row, col, 32)] = f2b(fmaxf(acc[nt][r4] + bv, 0.0f));
    }
  }
}

// ---------------- FFN2: hpk @ W2 + b2 -> sbuf (f32) ----------------
__global__ __launch_bounds__(256)
void ffn2_kernel(const unsigned short* __restrict__ hpk,
                 const unsigned short* __restrict__ Wl,
                 const float* __restrict__ b2,
                 float* __restrict__ sbuf) {
  int scene = blockIdx.x & 7, r = blockIdx.x >> 3;     // grid 480
  int rbg = r % 15, cg = r / 15;                       // cg 0..3
  int wave = threadIdx.x >> 6, lane = threadIdx.x & 63;
  int rb = scene * 60 + rbg * 4 + wave;
  accfrag_t acc[4];
  wavegemm<32>(hpk, Wl, rb, cg * 4, acc);
  int l16 = lane & 15, lq = lane >> 4;
#pragma unroll
  for (int nt = 0; nt < 4; nt++) {
    int col = cg * 64 + nt * 16 + l16;
    float bv = b2[col];
#pragma unroll
    for (int r4 = 0; r4 < 4; r4++) {
      int row = rb * 16 + lq * 4 + r4;
      sbuf[(size_t)row * DD + col] = acc[nt][r4] + bv;
    }
  }
}

// ---------------- LN2: (sbuf + yf) -> next-layer streams or d_out ----------------
template<bool LAST>
__global__ __launch_bounds__(256)
void ln2_kernel(const float* __restrict__ sbuf, float* __restrict__ yf,
                unsigned short* __restrict__ outpk, unsigned short* __restrict__ qkpk,
                const unsigned short* __restrict__ pe_b,
                const float* __restrict__ g, const float* __restrict__ bta,
                void* __restrict__ dout, const int* __restrict__ flag) {
  int m0 = swiz_m0(blockIdx.x);                        // grid 240
  int row = m0 + (threadIdx.x >> 3), sub = threadIdx.x & 7;
  const float* src = sbuf + (size_t)row * DD + sub * 32;
  const float* rs  = yf   + (size_t)row * DD + sub * 32;
  float v[32]; float s = 0.f, s2 = 0.f;
#pragma unroll
  for (int i = 0; i < 8; i++) {
    float4 t = *(const float4*)(src + i * 4);
    float4 u = *(const float4*)(rs + i * 4);
    float a0 = t.x + u.x, a1 = t.y + u.y, a2 = t.z + u.z, a3 = t.w + u.w;
    v[i*4+0]=a0; v[i*4+1]=a1; v[i*4+2]=a2; v[i*4+3]=a3;
    s += a0 + a1 + a2 + a3;
    s2 += a0*a0 + a1*a1 + a2*a2 + a3*a3;
  }
#pragma unroll
  for (int o = 1; o < 8; o <<= 1) { s += __shfl_xor(s, o); s2 += __shfl_xor(s2, o); }
  float mu = s * (1.0f/256.0f);
  float var = s2 * (1.0f/256.0f) - mu * mu;
  float rstd = 1.0f / sqrtf(fmaxf(var, 0.f) + 1e-5f);
  int c0 = sub * 32;
#pragma unroll
  for (int i = 0; i < 32; i++) v[i] = (v[i] - mu) * rstd * g[c0+i] + bta[c0+i];
  if (!LAST) {
    float* yo = yf + (size_t)row * DD + c0;
#pragma unroll
    for (int i = 0; i < 8; i++)
      *(float4*)(yo + i*4) = make_float4(v[i*4], v[i*4+1], v[i*4+2], v[i*4+3]);
    unsigned short* op = outpk + (((size_t)(row >> 4) * 8 + sub) << 9) + (size_t)(row & 15) * 8;
#pragma unroll
    for (int lqc = 0; lqc < 4; lqc++)
      *(uint4*)(op + lqc * 128) = pack8(&v[lqc * 8]);
    const unsigned short* pp = pe_b + (size_t)row * DD + c0;
    float q[32];
#pragma unroll
    for (int i = 0; i < 32; i++) q[i] = v[i] + b2f(pp[i]);
    unsigned short* qp = qkpk + (((size_t)(row >> 4) * 8 + sub) << 9) + (size_t)(row & 15) * 8;
#pragma unroll
    for (int lqc = 0; lqc < 4; lqc++)
      *(uint4*)(qp + lqc * 128) = pack8(&q[lqc * 8]);
  } else {
    int b = row / TT, t = row - b * TT;
    size_t o;
    if (t < MTOK)             o = (size_t)(b * MTOK + t) * DD + c0;
    else if (t < MTOK + NTOK) o = (size_t)BB * MTOK * DD + (size_t)(b * NTOK + (t - MTOK)) * DD + c0;
    else                      o = (size_t)BB * MTOK * DD + (size_t)BB * NTOK * DD
                                + (size_t)(b * LTOK + (t - MTOK - NTOK)) * DD + c0;
    if (*flag) {
      unsigned short* dp = (unsigned short*)dout + o;
#pragma unroll
      for (int lqc = 0; lqc < 4; lqc++)
        *(uint4*)(dp + lqc * 8) = pack8(&v[lqc * 8]);
    } else {
      float* dp = (float*)dout + o;
#pragma unroll
      for (int i = 0; i < 8; i++)
        *(float4*)(dp + i*4) = make_float4(v[i*4], v[i*4+1], v[i*4+2], v[i*4+3]);
    }
  }
}

// ---------------- launcher ----------------
extern "C" void kernel_launch(void* const* d_in, const int* in_sizes, int n_in,
                              void* d_out, int out_size, void* d_ws, size_t ws_size,
                              hipStream_t stream) {
  const void* map_tok   = d_in[0];
  const void* agent_tok = d_in[1];
  const void* light_tok = d_in[2];
  const void* map_pos   = d_in[3];
  const void* agent_pos = d_in[4];
  const void* light_pos = d_in[5];
  const void* Wq  = d_in[9];
  const void* bq  = d_in[10];
  const void* Wk  = d_in[11];
  const void* bk  = d_in[12];
  const void* Wv  = d_in[13];
  const void* bv  = d_in[14];
  const void* Wo  = d_in[15];
  const void* bo  = d_in[16];
  const void* W1  = d_in[17];
  const void* b1  = d_in[18];
  const void* W2  = d_in[19];
  const void* b2  = d_in[20];
  const void* ln1s = d_in[21];
  const void* ln1b = d_in[22];
  const void* ln2s = d_in[23];
  const void* ln2b = d_in[24];

  size_t off = 0;
  char* base = (char*)d_ws;
  auto take = [&](size_t bytes) { char* p = base + off; off += (bytes + 255) & ~(size_t)255; return (void*)p; };
  int*   flag  = (int*)take(256);
  float* posf  = (float*)take((size_t)BT * 2 * 4);
  float* pbuf  = (float*)take((size_t)FB_TOTAL * 4);
  unsigned short* pe_b = (unsigned short*)take((size_t)BT * DD * 2);
  float* out_f = (float*)take((size_t)BT * DD * 4);   // residual stream; LN1 writes y here
  unsigned short* pk1  = (unsigned short*)take((size_t)BT * DD * 2);  // outpk / xpk (aliased in time)
  unsigned short* qkpk = (unsigned short*)take((size_t)BT * DD * 2);
  unsigned short* QKV  = (unsigned short*)take((size_t)3 * BT * DD * 2);
  unsigned short* attnpk = (unsigned short*)take((size_t)BT * DD * 2);
  float* sbuf  = (float*)take((size_t)BT * DD * 4);   // wo-out then ffn2-out
  unsigned short* hpk  = (unsigned short*)take((size_t)BT * FFD * 2);
  int* idxb = (int*)take((size_t)BT * KNN * 4);
  unsigned short* Wqkvpk = (unsigned short*)take((size_t)NLAYERS * 3 * DD * DD * 2);
  unsigned short* Wopk   = (unsigned short*)take((size_t)NLAYERS * DD * DD * 2);
  unsigned short* W1pk   = (unsigned short*)take((size_t)NLAYERS * DD * FFD * 2);
  unsigned short* W2pk   = (unsigned short*)take((size_t)NLAYERS * DD * FFD * 2);

  detect_kernel<<<1, 256, 0, stream>>>(map_tok, flag);
  ParamSrc ps; ps.p[0]=bq; ps.p[1]=bk; ps.p[2]=bv; ps.p[3]=bo; ps.p[4]=b1;
  ps.p[5]=b2; ps.p[6]=ln1s; ps.p[7]=ln1b; ps.p[8]=ln2s; ps.p[9]=ln2b;
  ps.p[10]=map_pos; ps.p[11]=agent_pos; ps.p[12]=light_pos;
  conv_misc_kernel<<<BB + (FB_TOTAL + 255) / 256, 256, 0, stream>>>(ps, flag, pbuf, posf);

  PackSrc pw; pw.s[0]=Wq; pw.s[1]=Wk; pw.s[2]=Wv; pw.s[3]=Wo; pw.s[4]=W1; pw.s[5]=W2;
  packW_kernel<<<12288, 256, 0, stream>>>(pw, flag, Wqkvpk, Wopk, W1pk, W2pk);

  prep_kernel<<<BT, 256, 0, stream>>>(map_tok, agent_tok, light_tok, posf, flag,
                                      pe_b, out_f, pk1, qkpk);
  knn_kernel<<<1920, 256, 0, stream>>>(posf, idxb);

  for (int l = 0; l < NLAYERS; l++) {
    qkv_kernel<<<1440, 256, 0, stream>>>(qkpk, pk1, Wqkvpk + (size_t)l * 3 * 65536,
                                         pbuf, l, QKV);
    attn_kernel<<<BT, 256, 0, stream>>>(QKV, idxb, attnpk);
    wo_kernel<<<480, 256, 0, stream>>>(attnpk, Wopk + (size_t)l * 65536,
                                       pbuf + FB_BO + l * 256, out_f, sbuf);
    ln1_kernel<<<240, 256, 0, stream>>>(sbuf, out_f, pk1,
                                        pbuf + FB_LN1S + l * 256, pbuf + FB_LN1B + l * 256);
    ffn1_kernel<<<1920, 256, 0, stream>>>(pk1, W1pk + (size_t)l * 262144,
                                          pbuf + FB_B1 + l * 1024, hpk);
    ffn2_kernel<<<480, 256, 0, stream>>>(hpk, W2pk + (size_t)l * 262144,
                                         pbuf + FB_B2 + l * 256, sbuf);
    if (l < NLAYERS - 1)
      ln2_kernel<false><<<240, 256, 0, stream>>>(sbuf, out_f, pk1, qkpk, pe_b,
                                                 pbuf + FB_LN2S + l * 256, pbuf + FB_LN2B + l * 256,
                                                 d_out, flag);
    else
      ln2_kernel<true><<<240, 256, 0, stream>>>(sbuf, out_f, pk1, qkpk, pe_b,
                                                pbuf + FB_LN2S + l * 256, pbuf + FB_LN2B + l * 256,
                                                d_out, flag);
  }
}

// Round 3
// 473.228 us; speedup vs baseline: 1.1995x; 1.1010x over previous
//
#include <hip/hip_runtime.h>
#include <math.h>

#define BB 8
#define MTOK 768
#define NTOK 128
#define LTOK 64
#define TT 960          // MTOK+NTOK+LTOK
#define BT 7680         // BB*TT
#define DD 256
#define HH 8
#define HD 32
#define KNN 32
#define FFD 1024
#define NLAYERS 4
#define SCALE_ATT 0.17677669529663687f  // 1/sqrt(32)

typedef __attribute__((ext_vector_type(8))) short bfrag_t;   // 8 bf16 (4 VGPRs)
typedef __attribute__((ext_vector_type(4))) float accfrag_t; // 4 fp32 acc

__device__ __forceinline__ float b2f(unsigned short u) {
  union { unsigned int i; float f; } c; c.i = ((unsigned int)u) << 16; return c.f;
}
__device__ __forceinline__ unsigned short f2b(float f) {
  union { float f; unsigned int i; } c; c.f = f;
  return (unsigned short)((c.i + 0x7fffu + ((c.i >> 16) & 1u)) >> 16);
}
__device__ __forceinline__ float load_elem(const void* p, size_t i, int f) {
  return f ? b2f(((const unsigned short*)p)[i]) : ((const float*)p)[i];
}
// fragment-packed layout: element (row,k[col]) of [R x K] ->
//   ((row/16)*NKS + k/32)*512 + (((k>>3)&3)*16 + row%16)*8 + k%8
__device__ __forceinline__ size_t pk_addr(int row, int col, int nks) {
  return ((size_t)((row >> 4) * nks + (col >> 5)) << 9)
       + (size_t)(((((col >> 3) & 3) << 4) + (row & 15)) * 8 + (col & 7));
}
__device__ __forceinline__ uint4 pack8(const float* v) {
  uint4 u;
  u.x = (unsigned)f2b(v[0]) | ((unsigned)f2b(v[1]) << 16);
  u.y = (unsigned)f2b(v[2]) | ((unsigned)f2b(v[3]) << 16);
  u.z = (unsigned)f2b(v[4]) | ((unsigned)f2b(v[5]) << 16);
  u.w = (unsigned)f2b(v[6]) | ((unsigned)f2b(v[7]) << 16);
  return u;
}
// scene->XCD swizzle
__device__ __forceinline__ int swiz_tok(int blk) { return (blk & 7) * TT + (blk >> 3); }

// ---------------- dtype detector ----------------
__global__ __launch_bounds__(256)
void detect_kernel(const void* tok, int* flag) {
  __shared__ int cnt;
  if (threadIdx.x == 0) cnt = 0;
  __syncthreads();
  const unsigned short* u = (const unsigned short*)tok;
  int ok = 0;
  for (int i = threadIdx.x; i < 1024; i += 256) {
    int e = (u[i] >> 7) & 0xFF;
    if (e >= 100 && e <= 140) ok++;
  }
  atomicAdd(&cnt, ok);
  __syncthreads();
  if (threadIdx.x == 0) *flag = (cnt >= 922) ? 1 : 0;
}

// ---------------- positions + params -> fp32 ----------------
#define FB_BQ 0
#define FB_BK 1024
#define FB_BV 2048
#define FB_BO 3072
#define FB_B1 4096
#define FB_B2 8192
#define FB_LN1S 9216
#define FB_LN1B 10240
#define FB_LN2S 11264
#define FB_LN2B 12288
#define FB_TOTAL 13312
struct ParamSrc { const void* p[13]; };
__global__ __launch_bounds__(256)
void conv_misc_kernel(ParamSrc ps, const int* flag, float* __restrict__ dst,
                      float* __restrict__ posf) {
  int f = *flag;
  if (blockIdx.x < BB) {
    int b = blockIdx.x;
    for (int t = threadIdx.x; t < TT * 2; t += 256) {
      int tok = t >> 1, c = t & 1;
      const void* p; size_t idx;
      if (tok < MTOK)             { p = ps.p[10]; idx = (size_t)(b * MTOK + tok) * 2 + c; }
      else if (tok < MTOK + NTOK) { p = ps.p[11]; idx = (size_t)(b * NTOK + tok - MTOK) * 2 + c; }
      else                        { p = ps.p[12]; idx = (size_t)(b * LTOK + tok - MTOK - NTOK) * 2 + c; }
      posf[((size_t)b * TT + tok) * 2 + c] = load_elem(p, idx, f);
    }
    return;
  }
  int i = (blockIdx.x - BB) * 256 + threadIdx.x;
  if (i >= FB_TOTAL) return;
  int src; size_t off;
  if (i < 4096)      { src = i >> 10;              off = i & 1023; }
  else if (i < 8192) { src = 4;                    off = i - 4096; }
  else               { src = 5 + ((i - 8192) >> 10); off = (i - 8192) & 1023; }
  dst[i] = load_elem(ps.p[src], off, f);
}

// ---------------- pack all weights into fragment order ----------------
struct PackSrc { const void* s[6]; };
__global__ __launch_bounds__(256)
void packW_kernel(PackSrc w, const int* flag,
                  unsigned short* __restrict__ Wqkvpk, unsigned short* __restrict__ Wopk,
                  unsigned short* __restrict__ W1pk, unsigned short* __restrict__ W2pk) {
  int f = *flag;
  int id = blockIdx.x * 256 + threadIdx.x;
  const void* src; unsigned short* dst; int layer, e, K, N;
  if (id < 786432) {                    // Wq,Wk,Wv: 4 layers x 3 x 65536
    layer = id / 196608; int rest = id % 196608; int sel = rest / 65536; e = rest % 65536;
    src = w.s[sel]; dst = Wqkvpk + id; K = 256; N = 256;
  } else if (id < 1048576) {            // Wo
    int off = id - 786432; layer = off / 65536; e = off % 65536;
    src = w.s[3]; dst = Wopk + off; K = 256; N = 256;
  } else if (id < 2097152) {            // W1
    int off = id - 1048576; layer = off / 262144; e = off % 262144;
    src = w.s[4]; dst = W1pk + off; K = 256; N = 1024;
  } else {                              // W2
    int off = id - 2097152; layer = off / 262144; e = off % 262144;
    src = w.s[5]; dst = W2pk + off; K = 1024; N = 256;
  }
  int nks = K >> 5;
  int cb = e / (nks * 512);
  int ks = (e / 512) % nks;
  int lane = (e >> 3) & 63, j = e & 7;
  int col = cb * 16 + (lane & 15);
  int k = ks * 32 + (lane >> 4) * 8 + j;
  size_t si = (size_t)layer * K * N + (size_t)k * N + col;
  *dst = f ? ((const unsigned short*)src)[si] : f2b(((const float*)src)[si]);
}

// ---------------- prep: positional embedding + stream init ----------------
__global__ __launch_bounds__(256)
void prep_kernel(const void* mt, const void* at, const void* lt,
                 const float* __restrict__ posf, const int* flag,
                 unsigned short* __restrict__ pe_b, float* __restrict__ out_f,
                 unsigned short* __restrict__ pk1, unsigned short* __restrict__ qkpk) {
  int n = swiz_tok(blockIdx.x), d = threadIdx.x;
  int b = n / TT, t = n - b * TT;
  int f = *flag;
  const void* src; size_t si;
  if (t < MTOK)              { src = mt; si = (size_t)(b * MTOK + t) * DD + d; }
  else if (t < MTOK + NTOK)  { src = at; si = (size_t)(b * NTOK + (t - MTOK)) * DD + d; }
  else                       { src = lt; si = (size_t)(b * LTOK + (t - MTOK - NTOK)) * DD + d; }
  float x = load_elem(src, si, f);
  float px = posf[((size_t)b * TT + t) * 2 + 0];
  float py = posf[((size_t)b * TT + t) * 2 + 1];
  float coord = (d < 128) ? py : px;
  int j = d & 127;
  float expo = (float)(2 * (j >> 1)) / 128.0f;
  float dim_t = powf(10000.0f, expo);
  float e = coord * 6.283185307179586f / dim_t;
  float p = (j & 1) ? cosf(e) : sinf(e);
  size_t o = (size_t)n * DD + d;
  pe_b[o] = f2b(p);
  out_f[o] = x;
  size_t pa = pk_addr(n, d, 8);
  pk1[pa] = f2b(x);
  qkpk[pa] = f2b(x + p);
}

// ---------------- KNN: threshold-prune + bitonic top-32 (exact) ----------------
// u64 key = (d2_bits << 32) | local_idx  -> ascending order == (d2, idx) lex,
// which matches jax.lax.top_k(-d2) tie-breaking exactly.
__device__ __forceinline__ unsigned long long shfl_xor_u64(unsigned long long v, int m) {
  unsigned lo = (unsigned)v, hi = (unsigned)(v >> 32);
  lo = (unsigned)__shfl_xor((int)lo, m);
  hi = (unsigned)__shfl_xor((int)hi, m);
  return ((unsigned long long)hi << 32) | (unsigned long long)lo;
}
__device__ __forceinline__ unsigned long long shfl_u64(unsigned long long v, int srcLane) {
  unsigned lo = (unsigned)v, hi = (unsigned)(v >> 32);
  lo = (unsigned)__shfl((int)lo, srcLane);
  hi = (unsigned)__shfl((int)hi, srcLane);
  return ((unsigned long long)hi << 32) | (unsigned long long)lo;
}
// full 64-element cross-lane bitonic sort, ascending by lane id
__device__ __forceinline__ unsigned long long bitonic64(unsigned long long key, int lane) {
#pragma unroll
  for (int kk = 2; kk <= 64; kk <<= 1) {
#pragma unroll
    for (int j = kk >> 1; j > 0; j >>= 1) {
      unsigned long long other = shfl_xor_u64(key, j);
      bool small_ = (lane & j) == 0;
      bool dir = (lane & kk) == 0;
      bool keep = ((key < other) == (small_ == dir));
      key = keep ? key : other;
    }
  }
  return key;
}

__global__ __launch_bounds__(256)
void knn_kernel(const float* __restrict__ posf, int* __restrict__ idx_out) {
  __shared__ float sx[TT], sy[TT];
  __shared__ unsigned long long cbuf[4][64];
  int b = blockIdx.x & 7;
  int qbase = (blockIdx.x >> 3) * 4;
  for (int t = threadIdx.x; t < TT; t += 256) {
    sx[t] = posf[((size_t)b * TT + t) * 2 + 0];
    sy[t] = posf[((size_t)b * TT + t) * 2 + 1];
  }
  __syncthreads();
  int wave = threadIdx.x >> 6, lane = threadIdx.x & 63;
  int t = qbase + wave;
  float qx = sx[t], qy = sy[t];

  // 15 keys per lane covering all 960 points
  unsigned long long k[15];
#pragma unroll
  for (int c = 0; c < 15; c++) {
    int j = c * 64 + lane;
    float dx = qx - sx[j], dy = qy - sy[j];
    float d2 = __fadd_rn(__fmul_rn(dx, dx), __fmul_rn(dy, dy));
    k[c] = ((unsigned long long)__float_as_uint(d2) << 32) | (unsigned)j;
  }

  // per-lane min (tree)
  unsigned long long lm = k[0];
#pragma unroll
  for (int c = 1; c < 15; c++) lm = (k[c] < lm) ? k[c] : lm;

  // sort 64 lane-mins; the 32nd smallest is a provable upper bound on the
  // 32nd smallest key overall (32 distinct lanes each own a key <= it).
  unsigned long long sm = bitonic64(lm, lane);
  unsigned long long thr = shfl_u64(sm, 31);   // broadcast sorted[31]

  // count candidates <= thr, exclusive scan across wave
  int c_l = 0;
#pragma unroll
  for (int c = 0; c < 15; c++) c_l += (k[c] <= thr) ? 1 : 0;
  int inc = c_l;
#pragma unroll
  for (int o = 1; o < 64; o <<= 1) {
    int tt = __shfl_up(inc, o);
    inc += (lane >= o) ? tt : 0;
  }
  int total = __shfl(inc, 63);
  int pos = inc - c_l;

  if (total <= 64) {
    // compact candidates into per-wave LDS slots (one per lane), sort, emit
    unsigned long long* wb = cbuf[wave];
#pragma unroll
    for (int c = 0; c < 15; c++) {
      if (k[c] <= thr) { wb[pos] = k[c]; pos++; }
    }
    unsigned long long cand = (lane < total) ? wb[lane] : ~0ull;
    cand = bitonic64(cand, lane);
    if (lane < KNN)
      idx_out[((size_t)(b * TT + t)) * KNN + lane] = b * TT + (int)(cand & 0xFFFFFFFFu);
  } else {
    // rare exact fallback: 32x tournament extraction on u64 keys
    unsigned res = 0;
    for (int i = 0; i < KNN; i++) {
      unsigned long long m = k[0];
#pragma unroll
      for (int c = 1; c < 15; c++) m = (k[c] < m) ? k[c] : m;
#pragma unroll
      for (int o = 32; o > 0; o >>= 1) {
        unsigned long long om = shfl_xor_u64(m, o);
        m = (om < m) ? om : m;
      }
      if (lane == i) res = (unsigned)(m & 0xFFFFFFFFu);
      int owner = (int)(m & 63u), ch = (int)(((unsigned)(m & 0xFFFFFFFFu)) >> 6);
      if (lane == owner) {
#pragma unroll
        for (int c = 0; c < 15; c++) if (c == ch) k[c] = ~0ull;
      }
    }
    if (lane < KNN)
      idx_out[((size_t)(b * TT + t)) * KNN + lane] = b * TT + (int)res;
  }
}

// ---------------- wave GEMM: 16 rows x 64 cols, packed operands, no LDS ----------------
template<int NKS>
__device__ __forceinline__ void wavegemm(const unsigned short* __restrict__ Apk,
                                         const unsigned short* __restrict__ Bpk,
                                         int rb, int cb0, accfrag_t (&acc)[4]) {
  const int lane = threadIdx.x & 63;
  accfrag_t z = {0.f, 0.f, 0.f, 0.f};
#pragma unroll
  for (int nt = 0; nt < 4; nt++) acc[nt] = z;
  const unsigned short* ap = Apk + ((size_t)rb * NKS * 512 + lane * 8);
  const unsigned short* bp = Bpk + ((size_t)cb0 * NKS * 512 + lane * 8);
#pragma unroll 4
  for (int ks = 0; ks < NKS; ks++) {
    bfrag_t a = *(const bfrag_t*)(ap + ks * 512);
#pragma unroll
    for (int nt = 0; nt < 4; nt++) {
      bfrag_t b = *(const bfrag_t*)(bp + (size_t)(nt * NKS + ks) * 512);
      acc[nt] = __builtin_amdgcn_mfma_f32_16x16x32_bf16(a, b, acc[nt], 0, 0, 0);
    }
  }
}

// ---------------- QKV GEMM: grid 1440 (8 scenes x 15 rbg x 12 cg), 4 waves/block ----------------
__global__ __launch_bounds__(256)
void qkv_kernel(const unsigned short* __restrict__ qkpk,
                const unsigned short* __restrict__ outpk,
                const unsigned short* __restrict__ Wl,
                const float* __restrict__ pb, int l,
                unsigned short* __restrict__ QKV) {
  int scene = blockIdx.x & 7, r = blockIdx.x >> 3;
  int rbg = r % 15, cgall = r / 15;           // cgall 0..11
  int wave = threadIdx.x >> 6, lane = threadIdx.x & 63;
  int rb = scene * 60 + rbg * 4 + wave;
  int sel = cgall >> 2, cg = cgall & 3;
  const unsigned short* A = (sel < 2) ? qkpk : outpk;
  const unsigned short* B = Wl + sel * 65536;
  const float* bias = pb + sel * 1024 + l * 256;
  accfrag_t acc[4];
  wavegemm<8>(A, B, rb, cg * 4, acc);
  int l16 = lane & 15, lq = lane >> 4;
  unsigned short* C = QKV + (size_t)sel * BT * DD;
#pragma unroll
  for (int nt = 0; nt < 4; nt++) {
    int col = cg * 64 + nt * 16 + l16;
    float bv = bias[col];
#pragma unroll
    for (int r4 = 0; r4 < 4; r4++) {
      int row = rb * 16 + lq * 4 + r4;
      C[(size_t)row * DD + col] = f2b(acc[nt][r4] + bv);
    }
  }
}

// ---------------- attention (packed output) ----------------
__global__ __launch_bounds__(256)
void attn_kernel(const unsigned short* __restrict__ QKV,
                 const int* __restrict__ idx,
                 unsigned short* __restrict__ attnpk) {
  __shared__ unsigned short kn[KNN][DD + 8];
  __shared__ unsigned short vn[KNN][DD + 8];
  __shared__ float qs[DD];
  __shared__ float att[HH][KNN];
  __shared__ int nb[KNN];
  const unsigned short* Q = QKV;
  const unsigned short* K = QKV + (size_t)BT * DD;
  const unsigned short* V = QKV + 2 * (size_t)BT * DD;
  int n = swiz_tok(blockIdx.x), tid = threadIdx.x;
  if (tid < KNN) nb[tid] = idx[n * KNN + tid];
  qs[tid] = b2f(Q[(size_t)n * DD + tid]);
  __syncthreads();
#pragma unroll
  for (int p = 0; p < 4; p++) {
    int e = p * 256 + tid;
    int r = e >> 5, c8 = (e & 31) * 8;
    int srow = nb[r];
    *(uint4*)(&kn[r][c8]) = *(const uint4*)(K + (size_t)srow * DD + c8);
    *(uint4*)(&vn[r][c8]) = *(const uint4*)(V + (size_t)srow * DD + c8);
  }
  __syncthreads();
  int h = tid >> 5, kk = tid & 31;
  float dot = 0.0f;
#pragma unroll
  for (int d = 0; d < HD; d++) dot += qs[h * HD + d] * b2f(kn[kk][h * HD + d]);
  float sc = dot * SCALE_ATT;
  float mx = sc;
#pragma unroll
  for (int o = 16; o > 0; o >>= 1) mx = fmaxf(mx, __shfl_xor(mx, o, 32));
  float ex = expf(sc - mx);
  float sm = ex;
#pragma unroll
  for (int o = 16; o > 0; o >>= 1) sm += __shfl_xor(sm, o, 32);
  att[h][kk] = ex / sm;
  __syncthreads();
  int d = kk;
  float oacc = 0.0f;
#pragma unroll
  for (int k2 = 0; k2 < KNN; k2++) oacc += att[h][k2] * b2f(vn[k2][h * HD + d]);
  attnpk[pk_addr(n, tid, 8)] = f2b(oacc);
}

// ---------------- fused Wo GEMM + bias + resid + LN1 -> yf(f32) + xpk(packed) ----------------
// grid 480: one block = one 16-row block x all 256 cols; wave w owns cols [w*64, w*64+64)
__global__ __launch_bounds__(256)
void wo_ln1_kernel(const unsigned short* __restrict__ attnpk,
                   const unsigned short* __restrict__ Wl,
                   const float* __restrict__ bo,
                   float* __restrict__ yf,            // in: residual; out: LN1 result
                   unsigned short* __restrict__ xpk,
                   const float* __restrict__ g, const float* __restrict__ bta) {
  __shared__ float ps1[4][16], ps2[4][16];
  int scene = blockIdx.x & 7, rbs = blockIdx.x >> 3;   // rbs 0..59
  int wave = threadIdx.x >> 6, lane = threadIdx.x & 63;
  int rb = scene * 60 + rbs;
  accfrag_t acc[4];
  wavegemm<8>(attnpk, Wl, rb, wave * 4, acc);
  int l16 = lane & 15, lq = lane >> 4;
  float val[4][4];
  float s[4] = {0.f, 0.f, 0.f, 0.f}, s2[4] = {0.f, 0.f, 0.f, 0.f};
#pragma unroll
  for (int nt = 0; nt < 4; nt++) {
    int col = wave * 64 + nt * 16 + l16;
    float bv = bo[col];
#pragma unroll
    for (int r4 = 0; r4 < 4; r4++) {
      int row = rb * 16 + lq * 4 + r4;
      float x = acc[nt][r4] + bv + yf[(size_t)row * DD + col];
      val[nt][r4] = x; s[r4] += x; s2[r4] += x * x;
    }
  }
#pragma unroll
  for (int o = 1; o < 16; o <<= 1) {
#pragma unroll
    for (int r4 = 0; r4 < 4; r4++) { s[r4] += __shfl_xor(s[r4], o); s2[r4] += __shfl_xor(s2[r4], o); }
  }
  if (l16 == 0) {
#pragma unroll
    for (int r4 = 0; r4 < 4; r4++) { ps1[wave][lq * 4 + r4] = s[r4]; ps2[wave][lq * 4 + r4] = s2[r4]; }
  }
  __syncthreads();
  float mu[4], rstd[4];
#pragma unroll
  for (int r4 = 0; r4 < 4; r4++) {
    int r16 = lq * 4 + r4;
    float ts  = ps1[0][r16] + ps1[1][r16] + ps1[2][r16] + ps1[3][r16];
    float ts2 = ps2[0][r16] + ps2[1][r16] + ps2[2][r16] + ps2[3][r16];
    mu[r4] = ts * (1.0f / 256.0f);
    float var = ts2 * (1.0f / 256.0f) - mu[r4] * mu[r4];
    rstd[r4] = 1.0f / sqrtf(fmaxf(var, 0.f) + 1e-5f);
  }
#pragma unroll
  for (int nt = 0; nt < 4; nt++) {
    int col = wave * 64 + nt * 16 + l16;
    float gg = g[col], bb = bta[col];
#pragma unroll
    for (int r4 = 0; r4 < 4; r4++) {
      int row = rb * 16 + lq * 4 + r4;
      float y = (val[nt][r4] - mu[r4]) * rstd[r4] * gg + bb;
      yf[(size_t)row * DD + col] = y;
      xpk[pk_addr(row, col, 8)] = f2b(y);
    }
  }
}

// ---------------- FFN1: xpk @ W1 + b1, ReLU -> hpk (packed) ----------------
__global__ __launch_bounds__(256)
void ffn1_kernel(const unsigned short* __restrict__ xpk,
                 const unsigned short* __restrict__ Wl,
                 const float* __restrict__ b1,
                 unsigned short* __restrict__ hpk) {
  int scene = blockIdx.x & 7, r = blockIdx.x >> 3;     // grid 1920
  int rbg = r % 15, cg = r / 15;                       // cg 0..15
  int wave = threadIdx.x >> 6, lane = threadIdx.x & 63;
  int rb = scene * 60 + rbg * 4 + wave;
  accfrag_t acc[4];
  wavegemm<8>(xpk, Wl, rb, cg * 4, acc);
  int l16 = lane & 15, lq = lane >> 4;
#pragma unroll
  for (int nt = 0; nt < 4; nt++) {
    int col = cg * 64 + nt * 16 + l16;
    float bv = b1[col];
#pragma unroll
    for (int r4 = 0; r4 < 4; r4++) {
      int row = rb * 16 + lq * 4 + r4;
      hpk[pk_addr(row, col, 32)] = f2b(fmaxf(acc[nt][r4] + bv, 0.0f));
    }
  }
}

// ---------------- fused FFN2 GEMM + bias + resid + LN2 -> streams / d_out ----------------
// grid 480: one block = one 16-row block x all 256 cols
template<bool LAST>
__global__ __launch_bounds__(256)
void ffn2_ln2_kernel(const unsigned short* __restrict__ hpk,
                     const unsigned short* __restrict__ Wl,
                     const float* __restrict__ b2,
                     float* __restrict__ yf,            // in: residual; out (!LAST): LN2 result
                     unsigned short* __restrict__ outpk, unsigned short* __restrict__ qkpk,
                     const unsigned short* __restrict__ pe_b,
                     const float* __restrict__ g, const float* __restrict__ bta,
                     void* __restrict__ dout, const int* __restrict__ flag) {
  __shared__ float ps1[4][16], ps2[4][16];
  int scene = blockIdx.x & 7, rbs = blockIdx.x >> 3;   // rbs 0..59
  int wave = threadIdx.x >> 6, lane = threadIdx.x & 63;
  int rb = scene * 60 + rbs;
  accfrag_t acc[4];
  wavegemm<32>(hpk, Wl, rb, wave * 4, acc);
  int l16 = lane & 15, lq = lane >> 4;
  float val[4][4];
  float s[4] = {0.f, 0.f, 0.f, 0.f}, s2[4] = {0.f, 0.f, 0.f, 0.f};
#pragma unroll
  for (int nt = 0; nt < 4; nt++) {
    int col = wave * 64 + nt * 16 + l16;
    float bv = b2[col];
#pragma unroll
    for (int r4 = 0; r4 < 4; r4++) {
      int row = rb * 16 + lq * 4 + r4;
      float x = acc[nt][r4] + bv + yf[(size_t)row * DD + col];
      val[nt][r4] = x; s[r4] += x; s2[r4] += x * x;
    }
  }
#pragma unroll
  for (int o = 1; o < 16; o <<= 1) {
#pragma unroll
    for (int r4 = 0; r4 < 4; r4++) { s[r4] += __shfl_xor(s[r4], o); s2[r4] += __shfl_xor(s2[r4], o); }
  }
  if (l16 == 0) {
#pragma unroll
    for (int r4 = 0; r4 < 4; r4++) { ps1[wave][lq * 4 + r4] = s[r4]; ps2[wave][lq * 4 + r4] = s2[r4]; }
  }
  __syncthreads();
  float mu[4], rstd[4];
#pragma unroll
  for (int r4 = 0; r4 < 4; r4++) {
    int r16 = lq * 4 + r4;
    float ts  = ps1[0][r16] + ps1[1][r16] + ps1[2][r16] + ps1[3][r16];
    float ts2 = ps2[0][r16] + ps2[1][r16] + ps2[2][r16] + ps2[3][r16];
    mu[r4] = ts * (1.0f / 256.0f);
    float var = ts2 * (1.0f / 256.0f) - mu[r4] * mu[r4];
    rstd[r4] = 1.0f / sqrtf(fmaxf(var, 0.f) + 1e-5f);
  }
  int fl = LAST ? *flag : 0;
#pragma unroll
  for (int nt = 0; nt < 4; nt++) {
    int col = wave * 64 + nt * 16 + l16;
    float gg = g[col], bb = bta[col];
#pragma unroll
    for (int r4 = 0; r4 < 4; r4++) {
      int row = rb * 16 + lq * 4 + r4;
      float y = (val[nt][r4] - mu[r4]) * rstd[r4] * gg + bb;
      if (!LAST) {
        yf[(size_t)row * DD + col] = y;
        outpk[pk_addr(row, col, 8)] = f2b(y);
        float q = y + b2f(pe_b[(size_t)row * DD + col]);
        qkpk[pk_addr(row, col, 8)] = f2b(q);
      } else {
        int t = rbs * 16 + lq * 4 + r4;   // row = scene*TT + t
        size_t o;
        if (t < MTOK)             o = (size_t)(scene * MTOK + t) * DD + col;
        else if (t < MTOK + NTOK) o = (size_t)BB * MTOK * DD + (size_t)(scene * NTOK + (t - MTOK)) * DD + col;
        else                      o = (size_t)BB * MTOK * DD + (size_t)BB * NTOK * DD
                                    + (size_t)(scene * LTOK + (t - MTOK - NTOK)) * DD + col;
        if (fl) ((unsigned short*)dout)[o] = f2b(y);
        else    ((float*)dout)[o] = y;
      }
    }
  }
}

// ---------------- launcher ----------------
extern "C" void kernel_launch(void* const* d_in, const int* in_sizes, int n_in,
                              void* d_out, int out_size, void* d_ws, size_t ws_size,
                              hipStream_t stream) {
  const void* map_tok   = d_in[0];
  const void* agent_tok = d_in[1];
  const void* light_tok = d_in[2];
  const void* map_pos   = d_in[3];
  const void* agent_pos = d_in[4];
  const void* light_pos = d_in[5];
  const void* Wq  = d_in[9];
  const void* bq  = d_in[10];
  const void* Wk  = d_in[11];
  const void* bk  = d_in[12];
  const void* Wv  = d_in[13];
  const void* bv  = d_in[14];
  const void* Wo  = d_in[15];
  const void* bo  = d_in[16];
  const void* W1  = d_in[17];
  const void* b1  = d_in[18];
  const void* W2  = d_in[19];
  const void* b2  = d_in[20];
  const void* ln1s = d_in[21];
  const void* ln1b = d_in[22];
  const void* ln2s = d_in[23];
  const void* ln2b = d_in[24];

  size_t off = 0;
  char* base = (char*)d_ws;
  auto take = [&](size_t bytes) { char* p = base + off; off += (bytes + 255) & ~(size_t)255; return (void*)p; };
  int*   flag  = (int*)take(256);
  float* posf  = (float*)take((size_t)BT * 2 * 4);
  float* pbuf  = (float*)take((size_t)FB_TOTAL * 4);
  unsigned short* pe_b = (unsigned short*)take((size_t)BT * DD * 2);
  float* out_f = (float*)take((size_t)BT * DD * 4);   // residual stream; LN writes y here
  unsigned short* pk1  = (unsigned short*)take((size_t)BT * DD * 2);  // outpk / xpk (aliased in time)
  unsigned short* qkpk = (unsigned short*)take((size_t)BT * DD * 2);
  unsigned short* QKV  = (unsigned short*)take((size_t)3 * BT * DD * 2);
  unsigned short* attnpk = (unsigned short*)take((size_t)BT * DD * 2);
  unsigned short* hpk  = (unsigned short*)take((size_t)BT * FFD * 2);
  int* idxb = (int*)take((size_t)BT * KNN * 4);
  unsigned short* Wqkvpk = (unsigned short*)take((size_t)NLAYERS * 3 * DD * DD * 2);
  unsigned short* Wopk   = (unsigned short*)take((size_t)NLAYERS * DD * DD * 2);
  unsigned short* W1pk   = (unsigned short*)take((size_t)NLAYERS * DD * FFD * 2);
  unsigned short* W2pk   = (unsigned short*)take((size_t)NLAYERS * DD * FFD * 2);

  detect_kernel<<<1, 256, 0, stream>>>(map_tok, flag);
  ParamSrc ps; ps.p[0]=bq; ps.p[1]=bk; ps.p[2]=bv; ps.p[3]=bo; ps.p[4]=b1;
  ps.p[5]=b2; ps.p[6]=ln1s; ps.p[7]=ln1b; ps.p[8]=ln2s; ps.p[9]=ln2b;
  ps.p[10]=map_pos; ps.p[11]=agent_pos; ps.p[12]=light_pos;
  conv_misc_kernel<<<BB + (FB_TOTAL + 255) / 256, 256, 0, stream>>>(ps, flag, pbuf, posf);

  PackSrc pw; pw.s[0]=Wq; pw.s[1]=Wk; pw.s[2]=Wv; pw.s[3]=Wo; pw.s[4]=W1; pw.s[5]=W2;
  packW_kernel<<<12288, 256, 0, stream>>>(pw, flag, Wqkvpk, Wopk, W1pk, W2pk);

  prep_kernel<<<BT, 256, 0, stream>>>(map_tok, agent_tok, light_tok, posf, flag,
                                      pe_b, out_f, pk1, qkpk);
  knn_kernel<<<1920, 256, 0, stream>>>(posf, idxb);

  for (int l = 0; l < NLAYERS; l++) {
    qkv_kernel<<<1440, 256, 0, stream>>>(qkpk, pk1, Wqkvpk + (size_t)l * 3 * 65536,
                                         pbuf, l, QKV);
    attn_kernel<<<BT, 256, 0, stream>>>(QKV, idxb, attnpk);
    wo_ln1_kernel<<<480, 256, 0, stream>>>(attnpk, Wopk + (size_t)l * 65536,
                                           pbuf + FB_BO + l * 256, out_f, pk1,
                                           pbuf + FB_LN1S + l * 256, pbuf + FB_LN1B + l * 256);
    ffn1_kernel<<<1920, 256, 0, stream>>>(pk1, W1pk + (size_t)l * 262144,
                                          pbuf + FB_B1 + l * 1024, hpk);
    if (l < NLAYERS - 1)
      ffn2_ln2_kernel<false><<<480, 256, 0, stream>>>(hpk, W2pk + (size_t)l * 262144,
                                                      pbuf + FB_B2 + l * 256, out_f, pk1, qkpk, pe_b,
                                                      pbuf + FB_LN2S + l * 256, pbuf + FB_LN2B + l * 256,
                                                      d_out, flag);
    else
      ffn2_ln2_kernel<true><<<480, 256, 0, stream>>>(hpk, W2pk + (size_t)l * 262144,
                                                     pbuf + FB_B2 + l * 256, out_f, pk1, qkpk, pe_b,
                                                     pbuf + FB_LN2S + l * 256, pbuf + FB_LN2B + l * 256,
                                                     d_out, flag);
  }
}

// Round 4
// 429.911 us; speedup vs baseline: 1.3204x; 1.1008x over previous
//
#include <hip/hip_runtime.h>
#include <math.h>

#define BB 8
#define MTOK 768
#define NTOK 128
#define LTOK 64
#define TT 960          // MTOK+NTOK+LTOK
#define BT 7680         // BB*TT
#define DD 256
#define HH 8
#define HD 32
#define KNN 32
#define FFD 1024
#define NLAYERS 4
#define SCALE_ATT 0.17677669529663687f  // 1/sqrt(32)

typedef __attribute__((ext_vector_type(8))) short bfrag_t;   // 8 bf16 (4 VGPRs)
typedef __attribute__((ext_vector_type(4))) float accfrag_t; // 4 fp32 acc

__device__ __forceinline__ float b2f(unsigned short u) {
  union { unsigned int i; float f; } c; c.i = ((unsigned int)u) << 16; return c.f;
}
__device__ __forceinline__ unsigned short f2b(float f) {
  union { float f; unsigned int i; } c; c.f = f;
  return (unsigned short)((c.i + 0x7fffu + ((c.i >> 16) & 1u)) >> 16);
}
__device__ __forceinline__ float load_elem(const void* p, size_t i, int f) {
  return f ? b2f(((const unsigned short*)p)[i]) : ((const float*)p)[i];
}
// fragment-packed layout: element (row,k[col]) of [R x K] ->
//   ((row/16)*NKS + k/32)*512 + (((k>>3)&3)*16 + row%16)*8 + k%8
__device__ __forceinline__ size_t pk_addr(int row, int col, int nks) {
  return ((size_t)((row >> 4) * nks + (col >> 5)) << 9)
       + (size_t)(((((col >> 3) & 3) << 4) + (row & 15)) * 8 + (col & 7));
}
// scene->XCD swizzle
__device__ __forceinline__ int swiz_tok(int blk) { return (blk & 7) * TT + (blk >> 3); }

// ---------------- dtype detector ----------------
__global__ __launch_bounds__(256)
void detect_kernel(const void* tok, int* flag) {
  __shared__ int cnt;
  if (threadIdx.x == 0) cnt = 0;
  __syncthreads();
  const unsigned short* u = (const unsigned short*)tok;
  int ok = 0;
  for (int i = threadIdx.x; i < 1024; i += 256) {
    int e = (u[i] >> 7) & 0xFF;
    if (e >= 100 && e <= 140) ok++;
  }
  atomicAdd(&cnt, ok);
  __syncthreads();
  if (threadIdx.x == 0) *flag = (cnt >= 922) ? 1 : 0;
}

// ---------------- positions + params -> fp32 ----------------
#define FB_BQ 0
#define FB_BK 1024
#define FB_BV 2048
#define FB_BO 3072
#define FB_B1 4096
#define FB_B2 8192
#define FB_LN1S 9216
#define FB_LN1B 10240
#define FB_LN2S 11264
#define FB_LN2B 12288
#define FB_TOTAL 13312
struct ParamSrc { const void* p[13]; };
__global__ __launch_bounds__(256)
void conv_misc_kernel(ParamSrc ps, const int* flag, float* __restrict__ dst,
                      float* __restrict__ posf) {
  int f = *flag;
  if (blockIdx.x < BB) {
    int b = blockIdx.x;
    for (int t = threadIdx.x; t < TT * 2; t += 256) {
      int tok = t >> 1, c = t & 1;
      const void* p; size_t idx;
      if (tok < MTOK)             { p = ps.p[10]; idx = (size_t)(b * MTOK + tok) * 2 + c; }
      else if (tok < MTOK + NTOK) { p = ps.p[11]; idx = (size_t)(b * NTOK + tok - MTOK) * 2 + c; }
      else                        { p = ps.p[12]; idx = (size_t)(b * LTOK + tok - MTOK - NTOK) * 2 + c; }
      posf[((size_t)b * TT + tok) * 2 + c] = load_elem(p, idx, f);
    }
    return;
  }
  int i = (blockIdx.x - BB) * 256 + threadIdx.x;
  if (i >= FB_TOTAL) return;
  int src; size_t off;
  if (i < 4096)      { src = i >> 10;              off = i & 1023; }
  else if (i < 8192) { src = 4;                    off = i - 4096; }
  else               { src = 5 + ((i - 8192) >> 10); off = (i - 8192) & 1023; }
  dst[i] = load_elem(ps.p[src], off, f);
}

// ---------------- pack all weights into fragment order ----------------
struct PackSrc { const void* s[6]; };
__global__ __launch_bounds__(256)
void packW_kernel(PackSrc w, const int* flag,
                  unsigned short* __restrict__ Wqkvpk, unsigned short* __restrict__ Wopk,
                  unsigned short* __restrict__ W1pk, unsigned short* __restrict__ W2pk) {
  int f = *flag;
  int id = blockIdx.x * 256 + threadIdx.x;
  const void* src; unsigned short* dst; int layer, e, K, N;
  if (id < 786432) {                    // Wq,Wk,Wv: 4 layers x 3 x 65536
    layer = id / 196608; int rest = id % 196608; int sel = rest / 65536; e = rest % 65536;
    src = w.s[sel]; dst = Wqkvpk + id; K = 256; N = 256;
  } else if (id < 1048576) {            // Wo
    int off = id - 786432; layer = off / 65536; e = off % 65536;
    src = w.s[3]; dst = Wopk + off; K = 256; N = 256;
  } else if (id < 2097152) {            // W1
    int off = id - 1048576; layer = off / 262144; e = off % 262144;
    src = w.s[4]; dst = W1pk + off; K = 256; N = 1024;
  } else {                              // W2
    int off = id - 2097152; layer = off / 262144; e = off % 262144;
    src = w.s[5]; dst = W2pk + off; K = 1024; N = 256;
  }
  int nks = K >> 5;
  int cb = e / (nks * 512);
  int ks = (e / 512) % nks;
  int lane = (e >> 3) & 63, j = e & 7;
  int col = cb * 16 + (lane & 15);
  int k = ks * 32 + (lane >> 4) * 8 + j;
  size_t si = (size_t)layer * K * N + (size_t)k * N + col;
  *dst = f ? ((const unsigned short*)src)[si] : f2b(((const float*)src)[si]);
}

// ---------------- prep: positional embedding + stream init ----------------
__global__ __launch_bounds__(256)
void prep_kernel(const void* mt, const void* at, const void* lt,
                 const float* __restrict__ posf, const int* flag,
                 unsigned short* __restrict__ pe_b, float* __restrict__ out_f,
                 unsigned short* __restrict__ pk1, unsigned short* __restrict__ qkpk) {
  int n = swiz_tok(blockIdx.x), d = threadIdx.x;
  int b = n / TT, t = n - b * TT;
  int f = *flag;
  const void* src; size_t si;
  if (t < MTOK)              { src = mt; si = (size_t)(b * MTOK + t) * DD + d; }
  else if (t < MTOK + NTOK)  { src = at; si = (size_t)(b * NTOK + (t - MTOK)) * DD + d; }
  else                       { src = lt; si = (size_t)(b * LTOK + (t - MTOK - NTOK)) * DD + d; }
  float x = load_elem(src, si, f);
  float px = posf[((size_t)b * TT + t) * 2 + 0];
  float py = posf[((size_t)b * TT + t) * 2 + 1];
  float coord = (d < 128) ? py : px;
  int j = d & 127;
  float expo = (float)(2 * (j >> 1)) / 128.0f;
  float dim_t = powf(10000.0f, expo);
  float e = coord * 6.283185307179586f / dim_t;
  float p = (j & 1) ? cosf(e) : sinf(e);
  size_t o = (size_t)n * DD + d;
  pe_b[o] = f2b(p);
  out_f[o] = x;
  size_t pa = pk_addr(n, d, 8);
  pk1[pa] = f2b(x);
  qkpk[pa] = f2b(x + p);
}

// ---------------- KNN: threshold-prune + bitonic top-32 (exact) ----------------
__device__ __forceinline__ unsigned long long shfl_xor_u64(unsigned long long v, int m) {
  unsigned lo = (unsigned)v, hi = (unsigned)(v >> 32);
  lo = (unsigned)__shfl_xor((int)lo, m);
  hi = (unsigned)__shfl_xor((int)hi, m);
  return ((unsigned long long)hi << 32) | (unsigned long long)lo;
}
__device__ __forceinline__ unsigned long long shfl_u64(unsigned long long v, int srcLane) {
  unsigned lo = (unsigned)v, hi = (unsigned)(v >> 32);
  lo = (unsigned)__shfl((int)lo, srcLane);
  hi = (unsigned)__shfl((int)hi, srcLane);
  return ((unsigned long long)hi << 32) | (unsigned long long)lo;
}
__device__ __forceinline__ unsigned long long bitonic64(unsigned long long key, int lane) {
#pragma unroll
  for (int kk = 2; kk <= 64; kk <<= 1) {
#pragma unroll
    for (int j = kk >> 1; j > 0; j >>= 1) {
      unsigned long long other = shfl_xor_u64(key, j);
      bool small_ = (lane & j) == 0;
      bool dir = (lane & kk) == 0;
      bool keep = ((key < other) == (small_ == dir));
      key = keep ? key : other;
    }
  }
  return key;
}

__global__ __launch_bounds__(256)
void knn_kernel(const float* __restrict__ posf, int* __restrict__ idx_out) {
  __shared__ float sx[TT], sy[TT];
  __shared__ unsigned long long cbuf[4][64];
  int b = blockIdx.x & 7;
  int qbase = (blockIdx.x >> 3) * 4;
  for (int t = threadIdx.x; t < TT; t += 256) {
    sx[t] = posf[((size_t)b * TT + t) * 2 + 0];
    sy[t] = posf[((size_t)b * TT + t) * 2 + 1];
  }
  __syncthreads();
  int wave = threadIdx.x >> 6, lane = threadIdx.x & 63;
  int t = qbase + wave;
  float qx = sx[t], qy = sy[t];

  unsigned long long k[15];
#pragma unroll
  for (int c = 0; c < 15; c++) {
    int j = c * 64 + lane;
    float dx = qx - sx[j], dy = qy - sy[j];
    float d2 = __fadd_rn(__fmul_rn(dx, dx), __fmul_rn(dy, dy));
    k[c] = ((unsigned long long)__float_as_uint(d2) << 32) | (unsigned)j;
  }
  unsigned long long lm = k[0];
#pragma unroll
  for (int c = 1; c < 15; c++) lm = (k[c] < lm) ? k[c] : lm;

  unsigned long long sm = bitonic64(lm, lane);
  unsigned long long thr = shfl_u64(sm, 31);

  int c_l = 0;
#pragma unroll
  for (int c = 0; c < 15; c++) c_l += (k[c] <= thr) ? 1 : 0;
  int inc = c_l;
#pragma unroll
  for (int o = 1; o < 64; o <<= 1) {
    int tt = __shfl_up(inc, o);
    inc += (lane >= o) ? tt : 0;
  }
  int total = __shfl(inc, 63);
  int pos = inc - c_l;

  if (total <= 64) {
    unsigned long long* wb = cbuf[wave];
#pragma unroll
    for (int c = 0; c < 15; c++) {
      if (k[c] <= thr) { wb[pos] = k[c]; pos++; }
    }
    unsigned long long cand = (lane < total) ? wb[lane] : ~0ull;
    cand = bitonic64(cand, lane);
    if (lane < KNN)
      idx_out[((size_t)(b * TT + t)) * KNN + lane] = b * TT + (int)(cand & 0xFFFFFFFFu);
  } else {
    unsigned res = 0;
    for (int i = 0; i < KNN; i++) {
      unsigned long long m = k[0];
#pragma unroll
      for (int c = 1; c < 15; c++) m = (k[c] < m) ? k[c] : m;
#pragma unroll
      for (int o = 32; o > 0; o >>= 1) {
        unsigned long long om = shfl_xor_u64(m, o);
        m = (om < m) ? om : m;
      }
      if (lane == i) res = (unsigned)(m & 0xFFFFFFFFu);
      int owner = (int)(m & 63u), ch = (int)(((unsigned)(m & 0xFFFFFFFFu)) >> 6);
      if (lane == owner) {
#pragma unroll
        for (int c = 0; c < 15; c++) if (c == ch) k[c] = ~0ull;
      }
    }
    if (lane < KNN)
      idx_out[((size_t)(b * TT + t)) * KNN + lane] = b * TT + (int)res;
  }
}

// ---------------- wave GEMM: 16 rows x 64 cols, packed operands ----------------
template<int NKS>
__device__ __forceinline__ void wavegemm(const unsigned short* __restrict__ Apk,
                                         const unsigned short* __restrict__ Bpk,
                                         int rb, int cb0, accfrag_t (&acc)[4]) {
  const int lane = threadIdx.x & 63;
  accfrag_t z = {0.f, 0.f, 0.f, 0.f};
#pragma unroll
  for (int nt = 0; nt < 4; nt++) acc[nt] = z;
  const unsigned short* ap = Apk + ((size_t)rb * NKS * 512 + lane * 8);
  const unsigned short* bp = Bpk + ((size_t)cb0 * NKS * 512 + lane * 8);
#pragma unroll 4
  for (int ks = 0; ks < NKS; ks++) {
    bfrag_t a = *(const bfrag_t*)(ap + ks * 512);
#pragma unroll
    for (int nt = 0; nt < 4; nt++) {
      bfrag_t b = *(const bfrag_t*)(bp + (size_t)(nt * NKS + ks) * 512);
      acc[nt] = __builtin_amdgcn_mfma_f32_16x16x32_bf16(a, b, acc[nt], 0, 0, 0);
    }
  }
}

// ---------------- QKV GEMM: grid 1440 (8 scenes x 15 rbg x 12 cg), 4 waves/block ----------------
__global__ __launch_bounds__(256)
void qkv_kernel(const unsigned short* __restrict__ qkpk,
                const unsigned short* __restrict__ outpk,
                const unsigned short* __restrict__ Wl,
                const float* __restrict__ pb, int l,
                unsigned short* __restrict__ QKV) {
  int scene = blockIdx.x & 7, r = blockIdx.x >> 3;
  int rbg = r % 15, cgall = r / 15;           // cgall 0..11
  int wave = threadIdx.x >> 6, lane = threadIdx.x & 63;
  int rb = scene * 60 + rbg * 4 + wave;
  int sel = cgall >> 2, cg = cgall & 3;
  const unsigned short* A = (sel < 2) ? qkpk : outpk;
  const unsigned short* B = Wl + sel * 65536;
  const float* bias = pb + sel * 1024 + l * 256;
  accfrag_t acc[4];
  wavegemm<8>(A, B, rb, cg * 4, acc);
  int l16 = lane & 15, lq = lane >> 4;
  unsigned short* C = QKV + (size_t)sel * BT * DD;
#pragma unroll
  for (int nt = 0; nt < 4; nt++) {
    int col = cg * 64 + nt * 16 + l16;
    float bv = bias[col];
#pragma unroll
    for (int r4 = 0; r4 < 4; r4++) {
      int row = rb * 16 + lq * 4 + r4;
      C[(size_t)row * DD + col] = f2b(acc[nt][r4] + bv);
    }
  }
}

// ---------------- attention (packed output) ----------------
__global__ __launch_bounds__(256)
void attn_kernel(const unsigned short* __restrict__ QKV,
                 const int* __restrict__ idx,
                 unsigned short* __restrict__ attnpk) {
  __shared__ unsigned short kn[KNN][DD + 8];
  __shared__ unsigned short vn[KNN][DD + 8];
  __shared__ float qs[DD];
  __shared__ float att[HH][KNN];
  __shared__ int nb[KNN];
  const unsigned short* Q = QKV;
  const unsigned short* K = QKV + (size_t)BT * DD;
  const unsigned short* V = QKV + 2 * (size_t)BT * DD;
  int n = swiz_tok(blockIdx.x), tid = threadIdx.x;
  if (tid < KNN) nb[tid] = idx[n * KNN + tid];
  qs[tid] = b2f(Q[(size_t)n * DD + tid]);
  __syncthreads();
#pragma unroll
  for (int p = 0; p < 4; p++) {
    int e = p * 256 + tid;
    int r = e >> 5, c8 = (e & 31) * 8;
    int srow = nb[r];
    *(uint4*)(&kn[r][c8]) = *(const uint4*)(K + (size_t)srow * DD + c8);
    *(uint4*)(&vn[r][c8]) = *(const uint4*)(V + (size_t)srow * DD + c8);
  }
  __syncthreads();
  int h = tid >> 5, kk = tid & 31;
  float dot = 0.0f;
#pragma unroll
  for (int d = 0; d < HD; d++) dot += qs[h * HD + d] * b2f(kn[kk][h * HD + d]);
  float sc = dot * SCALE_ATT;
  float mx = sc;
#pragma unroll
  for (int o = 16; o > 0; o >>= 1) mx = fmaxf(mx, __shfl_xor(mx, o, 32));
  float ex = expf(sc - mx);
  float sm = ex;
#pragma unroll
  for (int o = 16; o > 0; o >>= 1) sm += __shfl_xor(sm, o, 32);
  att[h][kk] = ex / sm;
  __syncthreads();
  int d = kk;
  float oacc = 0.0f;
#pragma unroll
  for (int k2 = 0; k2 < KNN; k2++) oacc += att[h][k2] * b2f(vn[k2][h * HD + d]);
  attnpk[pk_addr(n, tid, 8)] = f2b(oacc);
}

// ---------------- fused block: Wo+resid+LN1 -> FFN1+ReLU -> FFN2+resid+LN2 ----------------
// grid 480: one block = one 16-row block x all 256 cols; wave w owns cols [w*64, w*64+64)
// in both LN epilogues, so the LN1 output y stays in registers as the LN2 residual.
template<bool LAST>
__global__ __launch_bounds__(256)
void ffn_block_kernel(const unsigned short* __restrict__ attnpk,
                      const unsigned short* __restrict__ Wo,
                      const unsigned short* __restrict__ W1,
                      const unsigned short* __restrict__ W2,
                      const float* __restrict__ bo,
                      const float* __restrict__ b1,
                      const float* __restrict__ b2,
                      float* __restrict__ yf,            // in: residual stream; out (!LAST): LN2
                      unsigned short* __restrict__ outpk, unsigned short* __restrict__ qkpk,
                      const unsigned short* __restrict__ pe_b,
                      const float* __restrict__ g1, const float* __restrict__ t1,
                      const float* __restrict__ g2, const float* __restrict__ t2,
                      void* __restrict__ dout, const int* __restrict__ flag) {
  __shared__ unsigned short xls[8 * 512];    // 16r x 256k packed (NKS=8), 8 KB
  __shared__ unsigned short hls[32 * 512];   // 16r x 1024k packed (NKS=32), 32 KB
  __shared__ float ps1[4][16], ps2[4][16];
  int scene = blockIdx.x & 7, rbs = blockIdx.x >> 3;   // rbs 0..59
  int wave = threadIdx.x >> 6, lane = threadIdx.x & 63;
  int rb = scene * 60 + rbs;
  int l16 = lane & 15, lq = lane >> 4;

  // ---- phase 1: Wo GEMM + bias + residual + LN1 -> y (regs) + xls (LDS packed)
  accfrag_t acc[4];
  wavegemm<8>(attnpk, Wo, rb, wave * 4, acc);
  float y[4][4];
  float s[4] = {0.f, 0.f, 0.f, 0.f}, s2[4] = {0.f, 0.f, 0.f, 0.f};
#pragma unroll
  for (int nt = 0; nt < 4; nt++) {
    int col = wave * 64 + nt * 16 + l16;
    float bv = bo[col];
#pragma unroll
    for (int r4 = 0; r4 < 4; r4++) {
      int row = rb * 16 + lq * 4 + r4;
      float x = acc[nt][r4] + bv + yf[(size_t)row * DD + col];
      y[nt][r4] = x; s[r4] += x; s2[r4] += x * x;
    }
  }
#pragma unroll
  for (int o = 1; o < 16; o <<= 1) {
#pragma unroll
    for (int r4 = 0; r4 < 4; r4++) { s[r4] += __shfl_xor(s[r4], o); s2[r4] += __shfl_xor(s2[r4], o); }
  }
  if (l16 == 0) {
#pragma unroll
    for (int r4 = 0; r4 < 4; r4++) { ps1[wave][lq * 4 + r4] = s[r4]; ps2[wave][lq * 4 + r4] = s2[r4]; }
  }
  __syncthreads();
#pragma unroll
  for (int r4 = 0; r4 < 4; r4++) {
    int r16 = lq * 4 + r4;
    float ts  = ps1[0][r16] + ps1[1][r16] + ps1[2][r16] + ps1[3][r16];
    float ts2 = ps2[0][r16] + ps2[1][r16] + ps2[2][r16] + ps2[3][r16];
    float mu = ts * (1.0f / 256.0f);
    float var = ts2 * (1.0f / 256.0f) - mu * mu;
    float rstd = 1.0f / sqrtf(fmaxf(var, 0.f) + 1e-5f);
#pragma unroll
    for (int nt = 0; nt < 4; nt++) {
      int col = wave * 64 + nt * 16 + l16;
      float v = (y[nt][r4] - mu) * rstd * g1[col] + t1[col];
      y[nt][r4] = v;
      xls[pk_addr(r16, col, 8)] = f2b(v);
    }
  }
  __syncthreads();

  // ---- phase 2: FFN1 (xls @ W1 + b1, ReLU) -> hls (LDS packed)
#pragma unroll
  for (int i = 0; i < 4; i++) {
    int cg = wave * 4 + i;
    accfrag_t a2[4];
    wavegemm<8>(xls, W1, 0, cg * 4, a2);
#pragma unroll
    for (int nt = 0; nt < 4; nt++) {
      int col = cg * 64 + nt * 16 + l16;
      float bv = b1[col];
#pragma unroll
      for (int r4 = 0; r4 < 4; r4++)
        hls[pk_addr(lq * 4 + r4, col, 32)] = f2b(fmaxf(a2[nt][r4] + bv, 0.0f));
    }
  }
  __syncthreads();

  // ---- phase 3: FFN2 (hls @ W2 + b2) + residual(y) + LN2
  accfrag_t a3[4];
  wavegemm<32>(hls, W2, 0, wave * 4, a3);
  float v2[4][4];
  float s3[4] = {0.f, 0.f, 0.f, 0.f}, s4[4] = {0.f, 0.f, 0.f, 0.f};
#pragma unroll
  for (int nt = 0; nt < 4; nt++) {
    int col = wave * 64 + nt * 16 + l16;
    float bv = b2[col];
#pragma unroll
    for (int r4 = 0; r4 < 4; r4++) {
      float x = a3[nt][r4] + bv + y[nt][r4];
      v2[nt][r4] = x; s3[r4] += x; s4[r4] += x * x;
    }
  }
#pragma unroll
  for (int o = 1; o < 16; o <<= 1) {
#pragma unroll
    for (int r4 = 0; r4 < 4; r4++) { s3[r4] += __shfl_xor(s3[r4], o); s4[r4] += __shfl_xor(s4[r4], o); }
  }
  if (l16 == 0) {
#pragma unroll
    for (int r4 = 0; r4 < 4; r4++) { ps1[wave][lq * 4 + r4] = s3[r4]; ps2[wave][lq * 4 + r4] = s4[r4]; }
  }
  __syncthreads();
  int fl = LAST ? *flag : 0;
#pragma unroll
  for (int r4 = 0; r4 < 4; r4++) {
    int r16 = lq * 4 + r4;
    float ts  = ps1[0][r16] + ps1[1][r16] + ps1[2][r16] + ps1[3][r16];
    float ts2 = ps2[0][r16] + ps2[1][r16] + ps2[2][r16] + ps2[3][r16];
    float mu = ts * (1.0f / 256.0f);
    float var = ts2 * (1.0f / 256.0f) - mu * mu;
    float rstd = 1.0f / sqrtf(fmaxf(var, 0.f) + 1e-5f);
#pragma unroll
    for (int nt = 0; nt < 4; nt++) {
      int col = wave * 64 + nt * 16 + l16;
      float yv = (v2[nt][r4] - mu) * rstd * g2[col] + t2[col];
      int row = rb * 16 + r16;
      if (!LAST) {
        yf[(size_t)row * DD + col] = yv;
        outpk[pk_addr(row, col, 8)] = f2b(yv);
        float q = yv + b2f(pe_b[(size_t)row * DD + col]);
        qkpk[pk_addr(row, col, 8)] = f2b(q);
      } else {
        int t = rbs * 16 + r16;   // token within scene
        size_t o;
        if (t < MTOK)             o = (size_t)(scene * MTOK + t) * DD + col;
        else if (t < MTOK + NTOK) o = (size_t)BB * MTOK * DD + (size_t)(scene * NTOK + (t - MTOK)) * DD + col;
        else                      o = (size_t)BB * MTOK * DD + (size_t)BB * NTOK * DD
                                    + (size_t)(scene * LTOK + (t - MTOK - NTOK)) * DD + col;
        if (fl) ((unsigned short*)dout)[o] = f2b(yv);
        else    ((float*)dout)[o] = yv;
      }
    }
  }
}

// ---------------- launcher ----------------
extern "C" void kernel_launch(void* const* d_in, const int* in_sizes, int n_in,
                              void* d_out, int out_size, void* d_ws, size_t ws_size,
                              hipStream_t stream) {
  const void* map_tok   = d_in[0];
  const void* agent_tok = d_in[1];
  const void* light_tok = d_in[2];
  const void* map_pos   = d_in[3];
  const void* agent_pos = d_in[4];
  const void* light_pos = d_in[5];
  const void* Wq  = d_in[9];
  const void* bq  = d_in[10];
  const void* Wk  = d_in[11];
  const void* bk  = d_in[12];
  const void* Wv  = d_in[13];
  const void* bv  = d_in[14];
  const void* Wo  = d_in[15];
  const void* bo  = d_in[16];
  const void* W1  = d_in[17];
  const void* b1  = d_in[18];
  const void* W2  = d_in[19];
  const void* b2  = d_in[20];
  const void* ln1s = d_in[21];
  const void* ln1b = d_in[22];
  const void* ln2s = d_in[23];
  const void* ln2b = d_in[24];

  size_t off = 0;
  char* base = (char*)d_ws;
  auto take = [&](size_t bytes) { char* p = base + off; off += (bytes + 255) & ~(size_t)255; return (void*)p; };
  int*   flag  = (int*)take(256);
  float* posf  = (float*)take((size_t)BT * 2 * 4);
  float* pbuf  = (float*)take((size_t)FB_TOTAL * 4);
  unsigned short* pe_b = (unsigned short*)take((size_t)BT * DD * 2);
  float* out_f = (float*)take((size_t)BT * DD * 4);   // residual stream (f32)
  unsigned short* pk1  = (unsigned short*)take((size_t)BT * DD * 2);  // outpk (packed LN2/x)
  unsigned short* qkpk = (unsigned short*)take((size_t)BT * DD * 2);
  unsigned short* QKV  = (unsigned short*)take((size_t)3 * BT * DD * 2);
  unsigned short* attnpk = (unsigned short*)take((size_t)BT * DD * 2);
  int* idxb = (int*)take((size_t)BT * KNN * 4);
  unsigned short* Wqkvpk = (unsigned short*)take((size_t)NLAYERS * 3 * DD * DD * 2);
  unsigned short* Wopk   = (unsigned short*)take((size_t)NLAYERS * DD * DD * 2);
  unsigned short* W1pk   = (unsigned short*)take((size_t)NLAYERS * DD * FFD * 2);
  unsigned short* W2pk   = (unsigned short*)take((size_t)NLAYERS * DD * FFD * 2);

  detect_kernel<<<1, 256, 0, stream>>>(map_tok, flag);
  ParamSrc ps; ps.p[0]=bq; ps.p[1]=bk; ps.p[2]=bv; ps.p[3]=bo; ps.p[4]=b1;
  ps.p[5]=b2; ps.p[6]=ln1s; ps.p[7]=ln1b; ps.p[8]=ln2s; ps.p[9]=ln2b;
  ps.p[10]=map_pos; ps.p[11]=agent_pos; ps.p[12]=light_pos;
  conv_misc_kernel<<<BB + (FB_TOTAL + 255) / 256, 256, 0, stream>>>(ps, flag, pbuf, posf);

  PackSrc pw; pw.s[0]=Wq; pw.s[1]=Wk; pw.s[2]=Wv; pw.s[3]=Wo; pw.s[4]=W1; pw.s[5]=W2;
  packW_kernel<<<12288, 256, 0, stream>>>(pw, flag, Wqkvpk, Wopk, W1pk, W2pk);

  prep_kernel<<<BT, 256, 0, stream>>>(map_tok, agent_tok, light_tok, posf, flag,
                                      pe_b, out_f, pk1, qkpk);
  knn_kernel<<<1920, 256, 0, stream>>>(posf, idxb);

  for (int l = 0; l < NLAYERS; l++) {
    qkv_kernel<<<1440, 256, 0, stream>>>(qkpk, pk1, Wqkvpk + (size_t)l * 3 * 65536,
                                         pbuf, l, QKV);
    attn_kernel<<<BT, 256, 0, stream>>>(QKV, idxb, attnpk);
    if (l < NLAYERS - 1)
      ffn_block_kernel<false><<<480, 256, 0, stream>>>(
          attnpk, Wopk + (size_t)l * 65536, W1pk + (size_t)l * 262144, W2pk + (size_t)l * 262144,
          pbuf + FB_BO + l * 256, pbuf + FB_B1 + l * 1024, pbuf + FB_B2 + l * 256,
          out_f, pk1, qkpk, pe_b,
          pbuf + FB_LN1S + l * 256, pbuf + FB_LN1B + l * 256,
          pbuf + FB_LN2S + l * 256, pbuf + FB_LN2B + l * 256,
          d_out, flag);
    else
      ffn_block_kernel<true><<<480, 256, 0, stream>>>(
          attnpk, Wopk + (size_t)l * 65536, W1pk + (size_t)l * 262144, W2pk + (size_t)l * 262144,
          pbuf + FB_BO + l * 256, pbuf + FB_B1 + l * 1024, pbuf + FB_B2 + l * 256,
          out_f, pk1, qkpk, pe_b,
          pbuf + FB_LN1S + l * 256, pbuf + FB_LN1B + l * 256,
          pbuf + FB_LN2S + l * 256, pbuf + FB_LN2B + l * 256,
          d_out, flag);
  }
}

// Round 5
// 409.335 us; speedup vs baseline: 1.3867x; 1.0503x over previous
//
#include <hip/hip_runtime.h>
#include <math.h>

#define BB 8
#define MTOK 768
#define NTOK 128
#define LTOK 64
#define TT 960          // MTOK+NTOK+LTOK
#define BT 7680         // BB*TT
#define DD 256
#define HH 8
#define HD 32
#define KNN 32
#define FFD 1024
#define NLAYERS 4
#define SCALE_ATT 0.17677669529663687f  // 1/sqrt(32)

typedef __attribute__((ext_vector_type(8))) short bfrag_t;   // 8 bf16 (4 VGPRs)
typedef __attribute__((ext_vector_type(4))) float accfrag_t; // 4 fp32 acc

__device__ __forceinline__ float b2f(unsigned short u) {
  union { unsigned int i; float f; } c; c.i = ((unsigned int)u) << 16; return c.f;
}
__device__ __forceinline__ unsigned short f2b(float f) {
  union { float f; unsigned int i; } c; c.f = f;
  return (unsigned short)((c.i + 0x7fffu + ((c.i >> 16) & 1u)) >> 16);
}
__device__ __forceinline__ float load_elem(const void* p, size_t i, int f) {
  return f ? b2f(((const unsigned short*)p)[i]) : ((const float*)p)[i];
}
// fragment-packed layout: element (row,k[col]) of [R x K] ->
//   ((row/16)*NKS + k/32)*512 + (((k>>3)&3)*16 + row%16)*8 + k%8
__device__ __forceinline__ size_t pk_addr(int row, int col, int nks) {
  return ((size_t)((row >> 4) * nks + (col >> 5)) << 9)
       + (size_t)(((((col >> 3) & 3) << 4) + (row & 15)) * 8 + (col & 7));
}
// scene->XCD swizzle
__device__ __forceinline__ int swiz_tok(int blk) { return (blk & 7) * TT + (blk >> 3); }

// ---------------- positions + params -> fp32 (with inline dtype detect) ----------------
#define FB_BQ 0
#define FB_BK 1024
#define FB_BV 2048
#define FB_BO 3072
#define FB_B1 4096
#define FB_B2 8192
#define FB_LN1S 9216
#define FB_LN1B 10240
#define FB_LN2S 11264
#define FB_LN2B 12288
#define FB_TOTAL 13312
struct ParamSrc { const void* p[13]; };
__global__ __launch_bounds__(256)
void conv_misc_kernel(ParamSrc ps, const void* tok, int* flagout,
                      float* __restrict__ dst, float* __restrict__ posf) {
  __shared__ int cnt;
  if (threadIdx.x == 0) cnt = 0;
  __syncthreads();
  const unsigned short* u = (const unsigned short*)tok;
  int ok = 0;
  for (int i = threadIdx.x; i < 1024; i += 256) {
    int e = (u[i] >> 7) & 0xFF;
    if (e >= 100 && e <= 140) ok++;
  }
  atomicAdd(&cnt, ok);
  __syncthreads();
  int f = (cnt >= 922) ? 1 : 0;
  if (blockIdx.x == 0 && threadIdx.x == 0) *flagout = f;
  if (blockIdx.x < BB) {
    int b = blockIdx.x;
    for (int t = threadIdx.x; t < TT * 2; t += 256) {
      int tok2 = t >> 1, c = t & 1;
      const void* p; size_t idx;
      if (tok2 < MTOK)             { p = ps.p[10]; idx = (size_t)(b * MTOK + tok2) * 2 + c; }
      else if (tok2 < MTOK + NTOK) { p = ps.p[11]; idx = (size_t)(b * NTOK + tok2 - MTOK) * 2 + c; }
      else                         { p = ps.p[12]; idx = (size_t)(b * LTOK + tok2 - MTOK - NTOK) * 2 + c; }
      posf[((size_t)b * TT + tok2) * 2 + c] = load_elem(p, idx, f);
    }
    return;
  }
  int i = (blockIdx.x - BB) * 256 + threadIdx.x;
  if (i >= FB_TOTAL) return;
  int src; size_t off;
  if (i < 4096)      { src = i >> 10;              off = i & 1023; }
  else if (i < 8192) { src = 4;                    off = i - 4096; }
  else               { src = 5 + ((i - 8192) >> 10); off = (i - 8192) & 1023; }
  dst[i] = load_elem(ps.p[src], off, f);
}

// ---------------- KNN helpers ----------------
__device__ __forceinline__ unsigned long long shfl_xor_u64(unsigned long long v, int m) {
  unsigned lo = (unsigned)v, hi = (unsigned)(v >> 32);
  lo = (unsigned)__shfl_xor((int)lo, m);
  hi = (unsigned)__shfl_xor((int)hi, m);
  return ((unsigned long long)hi << 32) | (unsigned long long)lo;
}
__device__ __forceinline__ unsigned long long shfl_u64(unsigned long long v, int srcLane) {
  unsigned lo = (unsigned)v, hi = (unsigned)(v >> 32);
  lo = (unsigned)__shfl((int)lo, srcLane);
  hi = (unsigned)__shfl((int)hi, srcLane);
  return ((unsigned long long)hi << 32) | (unsigned long long)lo;
}
__device__ __forceinline__ unsigned long long bitonic64(unsigned long long key, int lane) {
#pragma unroll
  for (int kk = 2; kk <= 64; kk <<= 1) {
#pragma unroll
    for (int j = kk >> 1; j > 0; j >>= 1) {
      unsigned long long other = shfl_xor_u64(key, j);
      bool small_ = (lane & j) == 0;
      bool dir = (lane & kk) == 0;
      bool keep = ((key < other) == (small_ == dir));
      key = keep ? key : other;
    }
  }
  return key;
}

// ---------------- mega setup: packW (coalesced) + prep + knn in one dispatch ----------------
// grid = 12288 (packW) + 7680 (prep) + 1920 (knn) = 21888
struct PackSrc { const void* s[6]; };
__global__ __launch_bounds__(256)
void mega_kernel(PackSrc w, const void* mt, const void* at, const void* lt,
                 const float* __restrict__ posf, const int* __restrict__ flag,
                 unsigned short* __restrict__ Wqkvpk, unsigned short* __restrict__ Wopk,
                 unsigned short* __restrict__ W1pk, unsigned short* __restrict__ W2pk,
                 unsigned short* __restrict__ pe_b, float* __restrict__ out_f,
                 unsigned short* __restrict__ pk1, unsigned short* __restrict__ qkpk,
                 int* __restrict__ idx_out) {
  __shared__ float sx[TT], sy[TT];
  __shared__ unsigned long long cbuf[4][64];
  int bid = blockIdx.x;
  if (bid < 12288) {
    // ---- packW: source-linear enumeration -> coalesced reads, local scatter writes
    int f = *flag;
    int id = bid * 256 + threadIdx.x;
    if (id < 786432) {                  // Wq,Wk,Wv (K=256,N=256)
      int layer = id / 196608, rest = id % 196608;
      int sel = rest >> 16, e = rest & 65535;
      int k = e >> 8, col = e & 255;
      const void* src = w.s[sel];
      size_t si = (size_t)layer * 65536 + e;
      Wqkvpk[(size_t)layer * 196608 + (size_t)sel * 65536 + pk_addr(col, k, 8)] =
          f ? ((const unsigned short*)src)[si] : f2b(((const float*)src)[si]);
    } else if (id < 1048576) {          // Wo (K=256,N=256)
      int off = id - 786432, layer = off >> 16, e = off & 65535;
      int k = e >> 8, col = e & 255;
      size_t si = (size_t)layer * 65536 + e;
      Wopk[(size_t)layer * 65536 + pk_addr(col, k, 8)] =
          f ? ((const unsigned short*)w.s[3])[si] : f2b(((const float*)w.s[3])[si]);
    } else if (id < 2097152) {          // W1 (K=256,N=1024)
      int off = id - 1048576, layer = off >> 18, e = off & 262143;
      int k = e >> 10, col = e & 1023;
      size_t si = (size_t)layer * 262144 + e;
      W1pk[(size_t)layer * 262144 + pk_addr(col, k, 8)] =
          f ? ((const unsigned short*)w.s[4])[si] : f2b(((const float*)w.s[4])[si]);
    } else {                            // W2 (K=1024,N=256)
      int off = id - 2097152, layer = off >> 18, e = off & 262143;
      int k = e >> 8, col = e & 255;
      size_t si = (size_t)layer * 262144 + e;
      W2pk[(size_t)layer * 262144 + pk_addr(col, k, 32)] =
          f ? ((const unsigned short*)w.s[5])[si] : f2b(((const float*)w.s[5])[si]);
    }
    return;
  }
  if (bid < 19968) {
    // ---- prep: positional embedding + stream init
    int n = swiz_tok(bid - 12288), d = threadIdx.x;
    int b = n / TT, t = n - b * TT;
    int f = *flag;
    const void* src; size_t si;
    if (t < MTOK)              { src = mt; si = (size_t)(b * MTOK + t) * DD + d; }
    else if (t < MTOK + NTOK)  { src = at; si = (size_t)(b * NTOK + (t - MTOK)) * DD + d; }
    else                       { src = lt; si = (size_t)(b * LTOK + (t - MTOK - NTOK)) * DD + d; }
    float x = load_elem(src, si, f);
    float px = posf[((size_t)b * TT + t) * 2 + 0];
    float py = posf[((size_t)b * TT + t) * 2 + 1];
    float coord = (d < 128) ? py : px;
    int j = d & 127;
    float expo = (float)(2 * (j >> 1)) / 128.0f;
    float dim_t = powf(10000.0f, expo);
    float e = coord * 6.283185307179586f / dim_t;
    float p = (j & 1) ? cosf(e) : sinf(e);
    size_t o = (size_t)n * DD + d;
    pe_b[o] = f2b(p);
    out_f[o] = x;
    size_t pa = pk_addr(n, d, 8);
    pk1[pa] = f2b(x);
    qkpk[pa] = f2b(x + p);
    return;
  }
  // ---- knn: threshold-prune + bitonic top-32 (exact)
  int kb = bid - 19968;
  int b = kb & 7;
  int qbase = (kb >> 3) * 4;
  for (int t = threadIdx.x; t < TT; t += 256) {
    sx[t] = posf[((size_t)b * TT + t) * 2 + 0];
    sy[t] = posf[((size_t)b * TT + t) * 2 + 1];
  }
  __syncthreads();
  int wave = threadIdx.x >> 6, lane = threadIdx.x & 63;
  int t = qbase + wave;
  float qx = sx[t], qy = sy[t];

  unsigned long long k[15];
#pragma unroll
  for (int c = 0; c < 15; c++) {
    int j = c * 64 + lane;
    float dx = qx - sx[j], dy = qy - sy[j];
    float d2 = __fadd_rn(__fmul_rn(dx, dx), __fmul_rn(dy, dy));
    k[c] = ((unsigned long long)__float_as_uint(d2) << 32) | (unsigned)j;
  }
  unsigned long long lm = k[0];
#pragma unroll
  for (int c = 1; c < 15; c++) lm = (k[c] < lm) ? k[c] : lm;

  unsigned long long sm = bitonic64(lm, lane);
  unsigned long long thr = shfl_u64(sm, 31);

  int c_l = 0;
#pragma unroll
  for (int c = 0; c < 15; c++) c_l += (k[c] <= thr) ? 1 : 0;
  int inc = c_l;
#pragma unroll
  for (int o = 1; o < 64; o <<= 1) {
    int tt = __shfl_up(inc, o);
    inc += (lane >= o) ? tt : 0;
  }
  int total = __shfl(inc, 63);
  int pos = inc - c_l;

  if (total <= 64) {
    unsigned long long* wb = cbuf[wave];
#pragma unroll
    for (int c = 0; c < 15; c++) {
      if (k[c] <= thr) { wb[pos] = k[c]; pos++; }
    }
    unsigned long long cand = (lane < total) ? wb[lane] : ~0ull;
    cand = bitonic64(cand, lane);
    if (lane < KNN)
      idx_out[((size_t)(b * TT + t)) * KNN + lane] = b * TT + (int)(cand & 0xFFFFFFFFu);
  } else {
    unsigned res = 0;
    for (int i = 0; i < KNN; i++) {
      unsigned long long m = k[0];
#pragma unroll
      for (int c = 1; c < 15; c++) m = (k[c] < m) ? k[c] : m;
#pragma unroll
      for (int o = 32; o > 0; o >>= 1) {
        unsigned long long om = shfl_xor_u64(m, o);
        m = (om < m) ? om : m;
      }
      if (lane == i) res = (unsigned)(m & 0xFFFFFFFFu);
      int owner = (int)(m & 63u), ch = (int)(((unsigned)(m & 0xFFFFFFFFu)) >> 6);
      if (lane == owner) {
#pragma unroll
        for (int c = 0; c < 15; c++) if (c == ch) k[c] = ~0ull;
      }
    }
    if (lane < KNN)
      idx_out[((size_t)(b * TT + t)) * KNN + lane] = b * TT + (int)res;
  }
}

// ---------------- wave GEMM: 16 rows x 64 cols, packed operands ----------------
template<int NKS>
__device__ __forceinline__ void wavegemm(const unsigned short* __restrict__ Apk,
                                         const unsigned short* __restrict__ Bpk,
                                         int rb, int cb0, accfrag_t (&acc)[4]) {
  const int lane = threadIdx.x & 63;
  accfrag_t z = {0.f, 0.f, 0.f, 0.f};
#pragma unroll
  for (int nt = 0; nt < 4; nt++) acc[nt] = z;
  const unsigned short* ap = Apk + ((size_t)rb * NKS * 512 + lane * 8);
  const unsigned short* bp = Bpk + ((size_t)cb0 * NKS * 512 + lane * 8);
#pragma unroll 4
  for (int ks = 0; ks < NKS; ks++) {
    bfrag_t a = *(const bfrag_t*)(ap + ks * 512);
#pragma unroll
    for (int nt = 0; nt < 4; nt++) {
      bfrag_t b = *(const bfrag_t*)(bp + (size_t)(nt * NKS + ks) * 512);
      acc[nt] = __builtin_amdgcn_mfma_f32_16x16x32_bf16(a, b, acc[nt], 0, 0, 0);
    }
  }
}

// ---------------- QKV GEMM (layer 0 only): grid 1440 ----------------
__global__ __launch_bounds__(256)
void qkv_kernel(const unsigned short* __restrict__ qkpk,
                const unsigned short* __restrict__ outpk,
                const unsigned short* __restrict__ Wl,
                const float* __restrict__ pb, int l,
                unsigned short* __restrict__ QKV) {
  int scene = blockIdx.x & 7, r = blockIdx.x >> 3;
  int rbg = r % 15, cgall = r / 15;           // cgall 0..11
  int wave = threadIdx.x >> 6, lane = threadIdx.x & 63;
  int rb = scene * 60 + rbg * 4 + wave;
  int sel = cgall >> 2, cg = cgall & 3;
  const unsigned short* A = (sel < 2) ? qkpk : outpk;
  const unsigned short* B = Wl + sel * 65536;
  const float* bias = pb + sel * 1024 + l * 256;
  accfrag_t acc[4];
  wavegemm<8>(A, B, rb, cg * 4, acc);
  int l16 = lane & 15, lq = lane >> 4;
  unsigned short* C = QKV + (size_t)sel * BT * DD;
#pragma unroll
  for (int nt = 0; nt < 4; nt++) {
    int col = cg * 64 + nt * 16 + l16;
    float bv = bias[col];
#pragma unroll
    for (int r4 = 0; r4 < 4; r4++) {
      int row = rb * 16 + lq * 4 + r4;
      C[(size_t)row * DD + col] = f2b(acc[nt][r4] + bv);
    }
  }
}

// ---------------- attention (packed output) ----------------
__global__ __launch_bounds__(256)
void attn_kernel(const unsigned short* __restrict__ QKV,
                 const int* __restrict__ idx,
                 unsigned short* __restrict__ attnpk) {
  __shared__ unsigned short kn[KNN][DD + 8];
  __shared__ unsigned short vn[KNN][DD + 8];
  __shared__ float qs[DD];
  __shared__ float att[HH][KNN];
  __shared__ int nb[KNN];
  const unsigned short* Q = QKV;
  const unsigned short* K = QKV + (size_t)BT * DD;
  const unsigned short* V = QKV + 2 * (size_t)BT * DD;
  int n = swiz_tok(blockIdx.x), tid = threadIdx.x;
  if (tid < KNN) nb[tid] = idx[n * KNN + tid];
  qs[tid] = b2f(Q[(size_t)n * DD + tid]);
  __syncthreads();
#pragma unroll
  for (int p = 0; p < 4; p++) {
    int e = p * 256 + tid;
    int r = e >> 5, c8 = (e & 31) * 8;
    int srow = nb[r];
    *(uint4*)(&kn[r][c8]) = *(const uint4*)(K + (size_t)srow * DD + c8);
    *(uint4*)(&vn[r][c8]) = *(const uint4*)(V + (size_t)srow * DD + c8);
  }
  __syncthreads();
  int h = tid >> 5, kk = tid & 31;
  float dot = 0.0f;
#pragma unroll
  for (int d = 0; d < HD; d++) dot += qs[h * HD + d] * b2f(kn[kk][h * HD + d]);
  float sc = dot * SCALE_ATT;
  float mx = sc;
#pragma unroll
  for (int o = 16; o > 0; o >>= 1) mx = fmaxf(mx, __shfl_xor(mx, o, 32));
  float ex = expf(sc - mx);
  float sm = ex;
#pragma unroll
  for (int o = 16; o > 0; o >>= 1) sm += __shfl_xor(sm, o, 32);
  att[h][kk] = ex / sm;
  __syncthreads();
  int d = kk;
  float oacc = 0.0f;
#pragma unroll
  for (int k2 = 0; k2 < KNN; k2++) oacc += att[h][k2] * b2f(vn[k2][h * HD + d]);
  attnpk[pk_addr(n, tid, 8)] = f2b(oacc);
}

// ---------------- fused block: Wo+resid+LN1 -> FFN1 -> FFN2+resid+LN2 [-> next QKV] ----------------
// grid 480: one block = one 16-row block x all 256 cols; wave w owns cols [w*64, w*64+64)
// in both LN epilogues, so the LN1 output y stays in registers as the LN2 residual.
// For !LAST, phase 4 projects next-layer Q/K/V straight from LDS (no qkv dispatch).
template<bool LAST>
__global__ __launch_bounds__(256)
void ffn_block_kernel(const unsigned short* __restrict__ attnpk,
                      const unsigned short* __restrict__ Wo,
                      const unsigned short* __restrict__ W1,
                      const unsigned short* __restrict__ W2,
                      const unsigned short* __restrict__ Wn,   // next-layer Wqkv (packed)
                      const float* __restrict__ bo,
                      const float* __restrict__ b1,
                      const float* __restrict__ b2,
                      const float* __restrict__ pb, int ln,    // bias base, next layer idx
                      float* __restrict__ yf,                  // residual stream (f32)
                      const unsigned short* __restrict__ pe_b,
                      const float* __restrict__ g1, const float* __restrict__ t1,
                      const float* __restrict__ g2, const float* __restrict__ t2,
                      unsigned short* __restrict__ QKV,
                      void* __restrict__ dout, const int* __restrict__ flag) {
  __shared__ unsigned short xls[8 * 512];    // 16r x 256k packed (NKS=8), 8 KB
  __shared__ unsigned short hls[32 * 512];   // 16r x 1024k packed (NKS=32), 32 KB
  __shared__ float ps1[4][16], ps2[4][16];
  int scene = blockIdx.x & 7, rbs = blockIdx.x >> 3;   // rbs 0..59
  int wave = threadIdx.x >> 6, lane = threadIdx.x & 63;
  int rb = scene * 60 + rbs;
  int l16 = lane & 15, lq = lane >> 4;

  // ---- phase 1: Wo GEMM + bias + residual + LN1 -> y (regs) + xls (LDS packed)
  accfrag_t acc[4];
  wavegemm<8>(attnpk, Wo, rb, wave * 4, acc);
  float y[4][4];
  float s[4] = {0.f, 0.f, 0.f, 0.f}, s2[4] = {0.f, 0.f, 0.f, 0.f};
#pragma unroll
  for (int nt = 0; nt < 4; nt++) {
    int col = wave * 64 + nt * 16 + l16;
    float bv = bo[col];
#pragma unroll
    for (int r4 = 0; r4 < 4; r4++) {
      int row = rb * 16 + lq * 4 + r4;
      float x = acc[nt][r4] + bv + yf[(size_t)row * DD + col];
      y[nt][r4] = x; s[r4] += x; s2[r4] += x * x;
    }
  }
#pragma unroll
  for (int o = 1; o < 16; o <<= 1) {
#pragma unroll
    for (int r4 = 0; r4 < 4; r4++) { s[r4] += __shfl_xor(s[r4], o); s2[r4] += __shfl_xor(s2[r4], o); }
  }
  if (l16 == 0) {
#pragma unroll
    for (int r4 = 0; r4 < 4; r4++) { ps1[wave][lq * 4 + r4] = s[r4]; ps2[wave][lq * 4 + r4] = s2[r4]; }
  }
  __syncthreads();
#pragma unroll
  for (int r4 = 0; r4 < 4; r4++) {
    int r16 = lq * 4 + r4;
    float ts  = ps1[0][r16] + ps1[1][r16] + ps1[2][r16] + ps1[3][r16];
    float ts2 = ps2[0][r16] + ps2[1][r16] + ps2[2][r16] + ps2[3][r16];
    float mu = ts * (1.0f / 256.0f);
    float var = ts2 * (1.0f / 256.0f) - mu * mu;
    float rstd = 1.0f / sqrtf(fmaxf(var, 0.f) + 1e-5f);
#pragma unroll
    for (int nt = 0; nt < 4; nt++) {
      int col = wave * 64 + nt * 16 + l16;
      float v = (y[nt][r4] - mu) * rstd * g1[col] + t1[col];
      y[nt][r4] = v;
      xls[pk_addr(r16, col, 8)] = f2b(v);
    }
  }
  __syncthreads();

  // ---- phase 2: FFN1 (xls @ W1 + b1, ReLU) -> hls (LDS packed)
#pragma unroll
  for (int i = 0; i < 4; i++) {
    int cg = wave * 4 + i;
    accfrag_t a2[4];
    wavegemm<8>(xls, W1, 0, cg * 4, a2);
#pragma unroll
    for (int nt = 0; nt < 4; nt++) {
      int col = cg * 64 + nt * 16 + l16;
      float bv = b1[col];
#pragma unroll
      for (int r4 = 0; r4 < 4; r4++)
        hls[pk_addr(lq * 4 + r4, col, 32)] = f2b(fmaxf(a2[nt][r4] + bv, 0.0f));
    }
  }
  __syncthreads();

  // ---- phase 3: FFN2 (hls @ W2 + b2) + residual(y) + LN2
  accfrag_t a3[4];
  wavegemm<32>(hls, W2, 0, wave * 4, a3);
  float v2[4][4];
  float s3[4] = {0.f, 0.f, 0.f, 0.f}, s4[4] = {0.f, 0.f, 0.f, 0.f};
#pragma unroll
  for (int nt = 0; nt < 4; nt++) {
    int col = wave * 64 + nt * 16 + l16;
    float bv = b2[col];
#pragma unroll
    for (int r4 = 0; r4 < 4; r4++) {
      float x = a3[nt][r4] + bv + y[nt][r4];
      v2[nt][r4] = x; s3[r4] += x; s4[r4] += x * x;
    }
  }
#pragma unroll
  for (int o = 1; o < 16; o <<= 1) {
#pragma unroll
    for (int r4 = 0; r4 < 4; r4++) { s3[r4] += __shfl_xor(s3[r4], o); s4[r4] += __shfl_xor(s4[r4], o); }
  }
  if (l16 == 0) {
#pragma unroll
    for (int r4 = 0; r4 < 4; r4++) { ps1[wave][lq * 4 + r4] = s3[r4]; ps2[wave][lq * 4 + r4] = s4[r4]; }
  }
  __syncthreads();     // after this barrier all waves are done reading hls (phase-3 GEMM)
  unsigned short* qkls = hls;   // reuse first 8 KB of hls for packed (y+pe)
  int fl = LAST ? *flag : 0;
#pragma unroll
  for (int r4 = 0; r4 < 4; r4++) {
    int r16 = lq * 4 + r4;
    float ts  = ps1[0][r16] + ps1[1][r16] + ps1[2][r16] + ps1[3][r16];
    float ts2 = ps2[0][r16] + ps2[1][r16] + ps2[2][r16] + ps2[3][r16];
    float mu = ts * (1.0f / 256.0f);
    float var = ts2 * (1.0f / 256.0f) - mu * mu;
    float rstd = 1.0f / sqrtf(fmaxf(var, 0.f) + 1e-5f);
#pragma unroll
    for (int nt = 0; nt < 4; nt++) {
      int col = wave * 64 + nt * 16 + l16;
      float yv = (v2[nt][r4] - mu) * rstd * g2[col] + t2[col];
      int row = rb * 16 + r16;
      if (!LAST) {
        yf[(size_t)row * DD + col] = yv;           // residual for next layer
        float q = yv + b2f(pe_b[(size_t)row * DD + col]);
        xls[pk_addr(r16, col, 8)] = f2b(yv);       // out (for V projection)
        qkls[pk_addr(r16, col, 8)] = f2b(q);       // out+pe (for Q/K projection)
      } else {
        int t = rbs * 16 + r16;   // token within scene
        size_t o;
        if (t < MTOK)             o = (size_t)(scene * MTOK + t) * DD + col;
        else if (t < MTOK + NTOK) o = (size_t)BB * MTOK * DD + (size_t)(scene * NTOK + (t - MTOK)) * DD + col;
        else                      o = (size_t)BB * MTOK * DD + (size_t)BB * NTOK * DD
                                    + (size_t)(scene * LTOK + (t - MTOK - NTOK)) * DD + col;
        if (fl) ((unsigned short*)dout)[o] = f2b(yv);
        else    ((float*)dout)[o] = yv;
      }
    }
  }

  // ---- phase 4 (!LAST): next-layer QKV projection straight from LDS
  if (!LAST) {
    __syncthreads();
#pragma unroll
    for (int i = 0; i < 3; i++) {
      int cgall = wave * 3 + i;            // 12 tiles: Q(0-3) K(4-7) V(8-11)
      int sel = cgall >> 2, cg = cgall & 3;
      const unsigned short* A = (sel < 2) ? qkls : xls;
      accfrag_t a4[4];
      wavegemm<8>(A, Wn + sel * 65536, 0, cg * 4, a4);
      const float* bias = pb + sel * 1024 + ln * 256;
      unsigned short* C = QKV + (size_t)sel * BT * DD;
#pragma unroll
      for (int nt = 0; nt < 4; nt++) {
        int col = cg * 64 + nt * 16 + l16;
        float bv = bias[col];
#pragma unroll
        for (int r4 = 0; r4 < 4; r4++) {
          int row = rb * 16 + lq * 4 + r4;
          C[(size_t)row * DD + col] = f2b(a4[nt][r4] + bv);
        }
      }
    }
  }
}

// ---------------- launcher ----------------
extern "C" void kernel_launch(void* const* d_in, const int* in_sizes, int n_in,
                              void* d_out, int out_size, void* d_ws, size_t ws_size,
                              hipStream_t stream) {
  const void* map_tok   = d_in[0];
  const void* agent_tok = d_in[1];
  const void* light_tok = d_in[2];
  const void* map_pos   = d_in[3];
  const void* agent_pos = d_in[4];
  const void* light_pos = d_in[5];
  const void* Wq  = d_in[9];
  const void* bq  = d_in[10];
  const void* Wk  = d_in[11];
  const void* bk  = d_in[12];
  const void* Wv  = d_in[13];
  const void* bv  = d_in[14];
  const void* Wo  = d_in[15];
  const void* bo  = d_in[16];
  const void* W1  = d_in[17];
  const void* b1  = d_in[18];
  const void* W2  = d_in[19];
  const void* b2  = d_in[20];
  const void* ln1s = d_in[21];
  const void* ln1b = d_in[22];
  const void* ln2s = d_in[23];
  const void* ln2b = d_in[24];

  size_t off = 0;
  char* base = (char*)d_ws;
  auto take = [&](size_t bytes) { char* p = base + off; off += (bytes + 255) & ~(size_t)255; return (void*)p; };
  int*   flag  = (int*)take(256);
  float* posf  = (float*)take((size_t)BT * 2 * 4);
  float* pbuf  = (float*)take((size_t)FB_TOTAL * 4);
  unsigned short* pe_b = (unsigned short*)take((size_t)BT * DD * 2);
  float* out_f = (float*)take((size_t)BT * DD * 4);   // residual stream (f32)
  unsigned short* pk1  = (unsigned short*)take((size_t)BT * DD * 2);  // layer-0 x packed
  unsigned short* qkpk = (unsigned short*)take((size_t)BT * DD * 2);  // layer-0 x+pe packed
  unsigned short* QKV  = (unsigned short*)take((size_t)3 * BT * DD * 2);
  unsigned short* attnpk = (unsigned short*)take((size_t)BT * DD * 2);
  int* idxb = (int*)take((size_t)BT * KNN * 4);
  unsigned short* Wqkvpk = (unsigned short*)take((size_t)NLAYERS * 3 * DD * DD * 2);
  unsigned short* Wopk   = (unsigned short*)take((size_t)NLAYERS * DD * DD * 2);
  unsigned short* W1pk   = (unsigned short*)take((size_t)NLAYERS * DD * FFD * 2);
  unsigned short* W2pk   = (unsigned short*)take((size_t)NLAYERS * DD * FFD * 2);

  ParamSrc ps; ps.p[0]=bq; ps.p[1]=bk; ps.p[2]=bv; ps.p[3]=bo; ps.p[4]=b1;
  ps.p[5]=b2; ps.p[6]=ln1s; ps.p[7]=ln1b; ps.p[8]=ln2s; ps.p[9]=ln2b;
  ps.p[10]=map_pos; ps.p[11]=agent_pos; ps.p[12]=light_pos;
  conv_misc_kernel<<<BB + (FB_TOTAL + 255) / 256, 256, 0, stream>>>(ps, map_tok, flag, pbuf, posf);

  PackSrc pw; pw.s[0]=Wq; pw.s[1]=Wk; pw.s[2]=Wv; pw.s[3]=Wo; pw.s[4]=W1; pw.s[5]=W2;
  mega_kernel<<<21888, 256, 0, stream>>>(pw, map_tok, agent_tok, light_tok, posf, flag,
                                         Wqkvpk, Wopk, W1pk, W2pk,
                                         pe_b, out_f, pk1, qkpk, idxb);

  qkv_kernel<<<1440, 256, 0, stream>>>(qkpk, pk1, Wqkvpk, pbuf, 0, QKV);

  for (int l = 0; l < NLAYERS; l++) {
    attn_kernel<<<BT, 256, 0, stream>>>(QKV, idxb, attnpk);
    if (l < NLAYERS - 1)
      ffn_block_kernel<false><<<480, 256, 0, stream>>>(
          attnpk, Wopk + (size_t)l * 65536, W1pk + (size_t)l * 262144, W2pk + (size_t)l * 262144,
          Wqkvpk + (size_t)(l + 1) * 196608,
          pbuf + FB_BO + l * 256, pbuf + FB_B1 + l * 1024, pbuf + FB_B2 + l * 256,
          pbuf, l + 1,
          out_f, pe_b,
          pbuf + FB_LN1S + l * 256, pbuf + FB_LN1B + l * 256,
          pbuf + FB_LN2S + l * 256, pbuf + FB_LN2B + l * 256,
          QKV, d_out, flag);
    else
      ffn_block_kernel<true><<<480, 256, 0, stream>>>(
          attnpk, Wopk + (size_t)l * 65536, W1pk + (size_t)l * 262144, W2pk + (size_t)l * 262144,
          Wqkvpk,
          pbuf + FB_BO + l * 256, pbuf + FB_B1 + l * 1024, pbuf + FB_B2 + l * 256,
          pbuf, 0,
          out_f, pe_b,
          pbuf + FB_LN1S + l * 256, pbuf + FB_LN1B + l * 256,
          pbuf + FB_LN2S + l * 256, pbuf + FB_LN2B + l * 256,
          QKV, d_out, flag);
  }
}

// Round 6
// 405.507 us; speedup vs baseline: 1.3998x; 1.0094x over previous
//
#include <hip/hip_runtime.h>
#include <math.h>

#define BB 8
#define MTOK 768
#define NTOK 128
#define LTOK 64
#define TT 960          // MTOK+NTOK+LTOK
#define BT 7680         // BB*TT
#define DD 256
#define HH 8
#define HD 32
#define KNN 32
#define FFD 1024
#define NLAYERS 4
#define SCALE_ATT 0.17677669529663687f  // 1/sqrt(32)

typedef __attribute__((ext_vector_type(8))) short bfrag_t;   // 8 bf16 (4 VGPRs)
typedef __attribute__((ext_vector_type(4))) float accfrag_t; // 4 fp32 acc

__device__ __forceinline__ float b2f(unsigned short u) {
  union { unsigned int i; float f; } c; c.i = ((unsigned int)u) << 16; return c.f;
}
__device__ __forceinline__ unsigned short f2b(float f) {
  union { float f; unsigned int i; } c; c.f = f;
  return (unsigned short)((c.i + 0x7fffu + ((c.i >> 16) & 1u)) >> 16);
}
__device__ __forceinline__ float load_elem(const void* p, size_t i, int f) {
  return f ? b2f(((const unsigned short*)p)[i]) : ((const float*)p)[i];
}
// fragment-packed layout: element (row,k[col]) of [R x K] ->
//   ((row/16)*NKS + k/32)*512 + (((k>>3)&3)*16 + row%16)*8 + k%8
__device__ __forceinline__ size_t pk_addr(int row, int col, int nks) {
  return ((size_t)((row >> 4) * nks + (col >> 5)) << 9)
       + (size_t)(((((col >> 3) & 3) << 4) + (row & 15)) * 8 + (col & 7));
}
// scene->XCD swizzle
__device__ __forceinline__ int swiz_tok(int blk) { return (blk & 7) * TT + (blk >> 3); }

// ---------------- positions + params -> fp32 (with inline dtype detect) ----------------
#define FB_BQ 0
#define FB_BK 1024
#define FB_BV 2048
#define FB_BO 3072
#define FB_B1 4096
#define FB_B2 8192
#define FB_LN1S 9216
#define FB_LN1B 10240
#define FB_LN2S 11264
#define FB_LN2B 12288
#define FB_TOTAL 13312
struct ParamSrc { const void* p[13]; };
__global__ __launch_bounds__(256)
void conv_misc_kernel(ParamSrc ps, const void* tok, int* flagout,
                      float* __restrict__ dst, float* __restrict__ posf) {
  __shared__ int cnt;
  if (threadIdx.x == 0) cnt = 0;
  __syncthreads();
  const unsigned short* u = (const unsigned short*)tok;
  int ok = 0;
  for (int i = threadIdx.x; i < 1024; i += 256) {
    int e = (u[i] >> 7) & 0xFF;
    if (e >= 100 && e <= 140) ok++;
  }
  atomicAdd(&cnt, ok);
  __syncthreads();
  int f = (cnt >= 922) ? 1 : 0;
  if (blockIdx.x == 0 && threadIdx.x == 0) *flagout = f;
  if (blockIdx.x < BB) {
    int b = blockIdx.x;
    for (int t = threadIdx.x; t < TT * 2; t += 256) {
      int tok2 = t >> 1, c = t & 1;
      const void* p; size_t idx;
      if (tok2 < MTOK)             { p = ps.p[10]; idx = (size_t)(b * MTOK + tok2) * 2 + c; }
      else if (tok2 < MTOK + NTOK) { p = ps.p[11]; idx = (size_t)(b * NTOK + tok2 - MTOK) * 2 + c; }
      else                         { p = ps.p[12]; idx = (size_t)(b * LTOK + tok2 - MTOK - NTOK) * 2 + c; }
      posf[((size_t)b * TT + tok2) * 2 + c] = load_elem(p, idx, f);
    }
    return;
  }
  int i = (blockIdx.x - BB) * 256 + threadIdx.x;
  if (i >= FB_TOTAL) return;
  int src; size_t off;
  if (i < 4096)      { src = i >> 10;              off = i & 1023; }
  else if (i < 8192) { src = 4;                    off = i - 4096; }
  else               { src = 5 + ((i - 8192) >> 10); off = (i - 8192) & 1023; }
  dst[i] = load_elem(ps.p[src], off, f);
}

// ---------------- KNN helpers ----------------
__device__ __forceinline__ unsigned long long shfl_xor_u64(unsigned long long v, int m) {
  unsigned lo = (unsigned)v, hi = (unsigned)(v >> 32);
  lo = (unsigned)__shfl_xor((int)lo, m);
  hi = (unsigned)__shfl_xor((int)hi, m);
  return ((unsigned long long)hi << 32) | (unsigned long long)lo;
}
__device__ __forceinline__ unsigned long long shfl_u64(unsigned long long v, int srcLane) {
  unsigned lo = (unsigned)v, hi = (unsigned)(v >> 32);
  lo = (unsigned)__shfl((int)lo, srcLane);
  hi = (unsigned)__shfl((int)hi, srcLane);
  return ((unsigned long long)hi << 32) | (unsigned long long)lo;
}
__device__ __forceinline__ unsigned long long bitonic64(unsigned long long key, int lane) {
#pragma unroll
  for (int kk = 2; kk <= 64; kk <<= 1) {
#pragma unroll
    for (int j = kk >> 1; j > 0; j >>= 1) {
      unsigned long long other = shfl_xor_u64(key, j);
      bool small_ = (lane & j) == 0;
      bool dir = (lane & kk) == 0;
      bool keep = ((key < other) == (small_ == dir));
      key = keep ? key : other;
    }
  }
  return key;
}

// ---------------- mega setup: packW (coalesced) + prep + knn in one dispatch ----------------
// grid = 12288 (packW) + 7680 (prep) + 1920 (knn) = 21888
struct PackSrc { const void* s[6]; };
__global__ __launch_bounds__(256)
void mega_kernel(PackSrc w, const void* mt, const void* at, const void* lt,
                 const float* __restrict__ posf, const int* __restrict__ flag,
                 unsigned short* __restrict__ Wqkvpk, unsigned short* __restrict__ Wopk,
                 unsigned short* __restrict__ W1pk, unsigned short* __restrict__ W2pk,
                 unsigned short* __restrict__ pe_b, float* __restrict__ out_f,
                 unsigned short* __restrict__ pk1, unsigned short* __restrict__ qkpk,
                 int* __restrict__ idx_out) {
  __shared__ float sx[TT], sy[TT];
  __shared__ unsigned long long cbuf[4][64];
  int bid = blockIdx.x;
  if (bid < 12288) {
    // ---- packW: source-linear enumeration -> coalesced reads, local scatter writes
    int f = *flag;
    int id = bid * 256 + threadIdx.x;
    if (id < 786432) {                  // Wq,Wk,Wv (K=256,N=256)
      int layer = id / 196608, rest = id % 196608;
      int sel = rest >> 16, e = rest & 65535;
      int k = e >> 8, col = e & 255;
      const void* src = w.s[sel];
      size_t si = (size_t)layer * 65536 + e;
      Wqkvpk[(size_t)layer * 196608 + (size_t)sel * 65536 + pk_addr(col, k, 8)] =
          f ? ((const unsigned short*)src)[si] : f2b(((const float*)src)[si]);
    } else if (id < 1048576) {          // Wo (K=256,N=256)
      int off = id - 786432, layer = off >> 16, e = off & 65535;
      int k = e >> 8, col = e & 255;
      size_t si = (size_t)layer * 65536 + e;
      Wopk[(size_t)layer * 65536 + pk_addr(col, k, 8)] =
          f ? ((const unsigned short*)w.s[3])[si] : f2b(((const float*)w.s[3])[si]);
    } else if (id < 2097152) {          // W1 (K=256,N=1024)
      int off = id - 1048576, layer = off >> 18, e = off & 262143;
      int k = e >> 10, col = e & 1023;
      size_t si = (size_t)layer * 262144 + e;
      W1pk[(size_t)layer * 262144 + pk_addr(col, k, 8)] =
          f ? ((const unsigned short*)w.s[4])[si] : f2b(((const float*)w.s[4])[si]);
    } else {                            // W2 (K=1024,N=256)
      int off = id - 2097152, layer = off >> 18, e = off & 262143;
      int k = e >> 8, col = e & 255;
      size_t si = (size_t)layer * 262144 + e;
      W2pk[(size_t)layer * 262144 + pk_addr(col, k, 32)] =
          f ? ((const unsigned short*)w.s[5])[si] : f2b(((const float*)w.s[5])[si]);
    }
    return;
  }
  if (bid < 19968) {
    // ---- prep: positional embedding + stream init
    int n = swiz_tok(bid - 12288), d = threadIdx.x;
    int b = n / TT, t = n - b * TT;
    int f = *flag;
    const void* src; size_t si;
    if (t < MTOK)              { src = mt; si = (size_t)(b * MTOK + t) * DD + d; }
    else if (t < MTOK + NTOK)  { src = at; si = (size_t)(b * NTOK + (t - MTOK)) * DD + d; }
    else                       { src = lt; si = (size_t)(b * LTOK + (t - MTOK - NTOK)) * DD + d; }
    float x = load_elem(src, si, f);
    float px = posf[((size_t)b * TT + t) * 2 + 0];
    float py = posf[((size_t)b * TT + t) * 2 + 1];
    float coord = (d < 128) ? py : px;
    int j = d & 127;
    float expo = (float)(2 * (j >> 1)) / 128.0f;
    float dim_t = powf(10000.0f, expo);
    float e = coord * 6.283185307179586f / dim_t;
    float p = (j & 1) ? cosf(e) : sinf(e);
    size_t o = (size_t)n * DD + d;
    pe_b[o] = f2b(p);
    out_f[o] = x;
    size_t pa = pk_addr(n, d, 8);
    pk1[pa] = f2b(x);
    qkpk[pa] = f2b(x + p);
    return;
  }
  // ---- knn: threshold-prune + bitonic top-32 (exact)
  int kb = bid - 19968;
  int b = kb & 7;
  int qbase = (kb >> 3) * 4;
  for (int t = threadIdx.x; t < TT; t += 256) {
    sx[t] = posf[((size_t)b * TT + t) * 2 + 0];
    sy[t] = posf[((size_t)b * TT + t) * 2 + 1];
  }
  __syncthreads();
  int wave = threadIdx.x >> 6, lane = threadIdx.x & 63;
  int t = qbase + wave;
  float qx = sx[t], qy = sy[t];

  unsigned long long k[15];
#pragma unroll
  for (int c = 0; c < 15; c++) {
    int j = c * 64 + lane;
    float dx = qx - sx[j], dy = qy - sy[j];
    float d2 = __fadd_rn(__fmul_rn(dx, dx), __fmul_rn(dy, dy));
    k[c] = ((unsigned long long)__float_as_uint(d2) << 32) | (unsigned)j;
  }
  unsigned long long lm = k[0];
#pragma unroll
  for (int c = 1; c < 15; c++) lm = (k[c] < lm) ? k[c] : lm;

  unsigned long long sm = bitonic64(lm, lane);
  unsigned long long thr = shfl_u64(sm, 31);

  int c_l = 0;
#pragma unroll
  for (int c = 0; c < 15; c++) c_l += (k[c] <= thr) ? 1 : 0;
  int inc = c_l;
#pragma unroll
  for (int o = 1; o < 64; o <<= 1) {
    int tt = __shfl_up(inc, o);
    inc += (lane >= o) ? tt : 0;
  }
  int total = __shfl(inc, 63);
  int pos = inc - c_l;

  if (total <= 64) {
    unsigned long long* wb = cbuf[wave];
#pragma unroll
    for (int c = 0; c < 15; c++) {
      if (k[c] <= thr) { wb[pos] = k[c]; pos++; }
    }
    unsigned long long cand = (lane < total) ? wb[lane] : ~0ull;
    cand = bitonic64(cand, lane);
    if (lane < KNN)
      idx_out[((size_t)(b * TT + t)) * KNN + lane] = b * TT + (int)(cand & 0xFFFFFFFFu);
  } else {
    unsigned res = 0;
    for (int i = 0; i < KNN; i++) {
      unsigned long long m = k[0];
#pragma unroll
      for (int c = 1; c < 15; c++) m = (k[c] < m) ? k[c] : m;
#pragma unroll
      for (int o = 32; o > 0; o >>= 1) {
        unsigned long long om = shfl_xor_u64(m, o);
        m = (om < m) ? om : m;
      }
      if (lane == i) res = (unsigned)(m & 0xFFFFFFFFu);
      int owner = (int)(m & 63u), ch = (int)(((unsigned)(m & 0xFFFFFFFFu)) >> 6);
      if (lane == owner) {
#pragma unroll
        for (int c = 0; c < 15; c++) if (c == ch) k[c] = ~0ull;
      }
    }
    if (lane < KNN)
      idx_out[((size_t)(b * TT + t)) * KNN + lane] = b * TT + (int)res;
  }
}

// ---------------- wave GEMM: 16 rows x NT*16 cols, packed operands ----------------
template<int NKS, int NT>
__device__ __forceinline__ void wavegemm(const unsigned short* __restrict__ Apk,
                                         const unsigned short* __restrict__ Bpk,
                                         int rb, int cb0, accfrag_t (&acc)[NT]) {
  const int lane = threadIdx.x & 63;
  accfrag_t z = {0.f, 0.f, 0.f, 0.f};
#pragma unroll
  for (int nt = 0; nt < NT; nt++) acc[nt] = z;
  const unsigned short* ap = Apk + ((size_t)rb * NKS * 512 + lane * 8);
  const unsigned short* bp = Bpk + ((size_t)cb0 * NKS * 512 + lane * 8);
#pragma unroll 4
  for (int ks = 0; ks < NKS; ks++) {
    bfrag_t a = *(const bfrag_t*)(ap + ks * 512);
#pragma unroll
    for (int nt = 0; nt < NT; nt++) {
      bfrag_t b = *(const bfrag_t*)(bp + (size_t)(nt * NKS + ks) * 512);
      acc[nt] = __builtin_amdgcn_mfma_f32_16x16x32_bf16(a, b, acc[nt], 0, 0, 0);
    }
  }
}

// ---------------- QKV GEMM (layer 0 only): grid 1440 ----------------
__global__ __launch_bounds__(256)
void qkv_kernel(const unsigned short* __restrict__ qkpk,
                const unsigned short* __restrict__ outpk,
                const unsigned short* __restrict__ Wl,
                const float* __restrict__ pb, int l,
                unsigned short* __restrict__ QKV) {
  int scene = blockIdx.x & 7, r = blockIdx.x >> 3;
  int rbg = r % 15, cgall = r / 15;           // cgall 0..11
  int wave = threadIdx.x >> 6, lane = threadIdx.x & 63;
  int rb = scene * 60 + rbg * 4 + wave;
  int sel = cgall >> 2, cg = cgall & 3;
  const unsigned short* A = (sel < 2) ? qkpk : outpk;
  const unsigned short* B = Wl + sel * 65536;
  const float* bias = pb + sel * 1024 + l * 256;
  accfrag_t acc[4];
  wavegemm<8,4>(A, B, rb, cg * 4, acc);
  int l16 = lane & 15, lq = lane >> 4;
  unsigned short* C = QKV + (size_t)sel * BT * DD;
#pragma unroll
  for (int nt = 0; nt < 4; nt++) {
    int col = cg * 64 + nt * 16 + l16;
    float bv = bias[col];
#pragma unroll
    for (int r4 = 0; r4 < 4; r4++) {
      int row = rb * 16 + lq * 4 + r4;
      C[(size_t)row * DD + col] = f2b(acc[nt][r4] + bv);
    }
  }
}

// ---------------- attention (packed output) ----------------
__global__ __launch_bounds__(256)
void attn_kernel(const unsigned short* __restrict__ QKV,
                 const int* __restrict__ idx,
                 unsigned short* __restrict__ attnpk) {
  __shared__ unsigned short kn[KNN][DD + 8];
  __shared__ unsigned short vn[KNN][DD + 8];
  __shared__ float qs[DD];
  __shared__ float att[HH][KNN];
  __shared__ int nb[KNN];
  const unsigned short* Q = QKV;
  const unsigned short* K = QKV + (size_t)BT * DD;
  const unsigned short* V = QKV + 2 * (size_t)BT * DD;
  int n = swiz_tok(blockIdx.x), tid = threadIdx.x;
  if (tid < KNN) nb[tid] = idx[n * KNN + tid];
  qs[tid] = b2f(Q[(size_t)n * DD + tid]);
  __syncthreads();
#pragma unroll
  for (int p = 0; p < 4; p++) {
    int e = p * 256 + tid;
    int r = e >> 5, c8 = (e & 31) * 8;
    int srow = nb[r];
    *(uint4*)(&kn[r][c8]) = *(const uint4*)(K + (size_t)srow * DD + c8);
    *(uint4*)(&vn[r][c8]) = *(const uint4*)(V + (size_t)srow * DD + c8);
  }
  __syncthreads();
  int h = tid >> 5, kk = tid & 31;
  float dot = 0.0f;
#pragma unroll
  for (int d = 0; d < HD; d++) dot += qs[h * HD + d] * b2f(kn[kk][h * HD + d]);
  float sc = dot * SCALE_ATT;
  float mx = sc;
#pragma unroll
  for (int o = 16; o > 0; o >>= 1) mx = fmaxf(mx, __shfl_xor(mx, o, 32));
  float ex = expf(sc - mx);
  float sm = ex;
#pragma unroll
  for (int o = 16; o > 0; o >>= 1) sm += __shfl_xor(sm, o, 32);
  att[h][kk] = ex / sm;
  __syncthreads();
  int d = kk;
  float oacc = 0.0f;
#pragma unroll
  for (int k2 = 0; k2 < KNN; k2++) oacc += att[h][k2] * b2f(vn[k2][h * HD + d]);
  attnpk[pk_addr(n, tid, 8)] = f2b(oacc);
}

// ---------------- fused block: Wo+resid+LN1 -> FFN1 -> FFN2+resid+LN2 [-> next QKV] ----------------
// grid 480 x 512 threads (8 waves). One block = one 16-row block x all 256 cols.
// Wave w owns cols [w*32, w*32+32) in phases 1 and 3, so the LN1 output y stays in
// registers as the LN2 residual. Phase 2: 8 FFN1 tiles/wave. Phase 4 (!LAST):
// Q -> waves 0-3 (4 tiles), K -> waves 4-7 (4 tiles), V -> all waves (2 tiles).
template<bool LAST>
__global__ __launch_bounds__(512)
void ffn_block_kernel(const unsigned short* __restrict__ attnpk,
                      const unsigned short* __restrict__ Wo,
                      const unsigned short* __restrict__ W1,
                      const unsigned short* __restrict__ W2,
                      const unsigned short* __restrict__ Wn,   // next-layer Wqkv (packed)
                      const float* __restrict__ bo,
                      const float* __restrict__ b1,
                      const float* __restrict__ b2,
                      const float* __restrict__ pb, int ln,    // bias base, next layer idx
                      float* __restrict__ yf,                  // residual stream (f32)
                      const unsigned short* __restrict__ pe_b,
                      const float* __restrict__ g1, const float* __restrict__ t1,
                      const float* __restrict__ g2, const float* __restrict__ t2,
                      unsigned short* __restrict__ QKV,
                      void* __restrict__ dout, const int* __restrict__ flag) {
  __shared__ unsigned short xls[8 * 512];    // 16r x 256k packed (NKS=8), 8 KB
  __shared__ unsigned short hls[32 * 512];   // 16r x 1024k packed (NKS=32), 32 KB
  __shared__ float ps1[8][16], ps2[8][16];
  int scene = blockIdx.x & 7, rbs = blockIdx.x >> 3;   // rbs 0..59
  int wave = threadIdx.x >> 6, lane = threadIdx.x & 63;
  int rb = scene * 60 + rbs;
  int l16 = lane & 15, lq = lane >> 4;

  // ---- phase 1: Wo GEMM (2 tiles/wave) + bias + residual + LN1 -> y (regs) + xls
  accfrag_t acc[2];
  wavegemm<8,2>(attnpk, Wo, rb, wave * 2, acc);
  float y[2][4];
  float s[4] = {0.f, 0.f, 0.f, 0.f}, s2[4] = {0.f, 0.f, 0.f, 0.f};
#pragma unroll
  for (int nt = 0; nt < 2; nt++) {
    int col = wave * 32 + nt * 16 + l16;
    float bv = bo[col];
#pragma unroll
    for (int r4 = 0; r4 < 4; r4++) {
      int row = rb * 16 + lq * 4 + r4;
      float x = acc[nt][r4] + bv + yf[(size_t)row * DD + col];
      y[nt][r4] = x; s[r4] += x; s2[r4] += x * x;
    }
  }
#pragma unroll
  for (int o = 1; o < 16; o <<= 1) {
#pragma unroll
    for (int r4 = 0; r4 < 4; r4++) { s[r4] += __shfl_xor(s[r4], o); s2[r4] += __shfl_xor(s2[r4], o); }
  }
  if (l16 == 0) {
#pragma unroll
    for (int r4 = 0; r4 < 4; r4++) { ps1[wave][lq * 4 + r4] = s[r4]; ps2[wave][lq * 4 + r4] = s2[r4]; }
  }
  __syncthreads();
#pragma unroll
  for (int r4 = 0; r4 < 4; r4++) {
    int r16 = lq * 4 + r4;
    float ts = 0.f, ts2 = 0.f;
#pragma unroll
    for (int wv = 0; wv < 8; wv++) { ts += ps1[wv][r16]; ts2 += ps2[wv][r16]; }
    float mu = ts * (1.0f / 256.0f);
    float var = ts2 * (1.0f / 256.0f) - mu * mu;
    float rstd = 1.0f / sqrtf(fmaxf(var, 0.f) + 1e-5f);
#pragma unroll
    for (int nt = 0; nt < 2; nt++) {
      int col = wave * 32 + nt * 16 + l16;
      float v = (y[nt][r4] - mu) * rstd * g1[col] + t1[col];
      y[nt][r4] = v;
      xls[pk_addr(r16, col, 8)] = f2b(v);
    }
  }
  __syncthreads();

  // ---- phase 2: FFN1 (xls @ W1 + b1, ReLU) -> hls; 8 tiles/wave as 2x4
#pragma unroll
  for (int half = 0; half < 2; half++) {
    int cb = wave * 8 + half * 4;
    accfrag_t a2[4];
    wavegemm<8,4>(xls, W1, 0, cb, a2);
#pragma unroll
    for (int nt = 0; nt < 4; nt++) {
      int col = (cb + nt) * 16 + l16;
      float bv = b1[col];
#pragma unroll
      for (int r4 = 0; r4 < 4; r4++)
        hls[pk_addr(lq * 4 + r4, col, 32)] = f2b(fmaxf(a2[nt][r4] + bv, 0.0f));
    }
  }
  __syncthreads();

  // ---- phase 3: FFN2 (hls @ W2 + b2, 2 tiles/wave) + residual(y) + LN2
  accfrag_t a3[2];
  wavegemm<32,2>(hls, W2, 0, wave * 2, a3);
  float v2[2][4];
  float s3[4] = {0.f, 0.f, 0.f, 0.f}, s4[4] = {0.f, 0.f, 0.f, 0.f};
#pragma unroll
  for (int nt = 0; nt < 2; nt++) {
    int col = wave * 32 + nt * 16 + l16;
    float bv = b2[col];
#pragma unroll
    for (int r4 = 0; r4 < 4; r4++) {
      float x = a3[nt][r4] + bv + y[nt][r4];
      v2[nt][r4] = x; s3[r4] += x; s4[r4] += x * x;
    }
  }
#pragma unroll
  for (int o = 1; o < 16; o <<= 1) {
#pragma unroll
    for (int r4 = 0; r4 < 4; r4++) { s3[r4] += __shfl_xor(s3[r4], o); s4[r4] += __shfl_xor(s4[r4], o); }
  }
  if (l16 == 0) {
#pragma unroll
    for (int r4 = 0; r4 < 4; r4++) { ps1[wave][lq * 4 + r4] = s3[r4]; ps2[wave][lq * 4 + r4] = s4[r4]; }
  }
  __syncthreads();     // all waves done reading hls (phase-3 GEMM) after this
  unsigned short* qkls = hls;   // reuse first 8 KB of hls for packed (y+pe)
  int fl = LAST ? *flag : 0;
#pragma unroll
  for (int r4 = 0; r4 < 4; r4++) {
    int r16 = lq * 4 + r4;
    float ts = 0.f, ts2 = 0.f;
#pragma unroll
    for (int wv = 0; wv < 8; wv++) { ts += ps1[wv][r16]; ts2 += ps2[wv][r16]; }
    float mu = ts * (1.0f / 256.0f);
    float var = ts2 * (1.0f / 256.0f) - mu * mu;
    float rstd = 1.0f / sqrtf(fmaxf(var, 0.f) + 1e-5f);
#pragma unroll
    for (int nt = 0; nt < 2; nt++) {
      int col = wave * 32 + nt * 16 + l16;
      float yv = (v2[nt][r4] - mu) * rstd * g2[col] + t2[col];
      int row = rb * 16 + r16;
      if (!LAST) {
        yf[(size_t)row * DD + col] = yv;           // residual for next layer
        float q = yv + b2f(pe_b[(size_t)row * DD + col]);
        xls[pk_addr(r16, col, 8)] = f2b(yv);       // out (for V projection)
        qkls[pk_addr(r16, col, 8)] = f2b(q);       // out+pe (for Q/K projection)
      } else {
        int t = rbs * 16 + r16;   // token within scene
        size_t o;
        if (t < MTOK)             o = (size_t)(scene * MTOK + t) * DD + col;
        else if (t < MTOK + NTOK) o = (size_t)BB * MTOK * DD + (size_t)(scene * NTOK + (t - MTOK)) * DD + col;
        else                      o = (size_t)BB * MTOK * DD + (size_t)BB * NTOK * DD
                                    + (size_t)(scene * LTOK + (t - MTOK - NTOK)) * DD + col;
        if (fl) ((unsigned short*)dout)[o] = f2b(yv);
        else    ((float*)dout)[o] = yv;
      }
    }
  }

  // ---- phase 4 (!LAST): next-layer QKV projection straight from LDS
  if (!LAST) {
    __syncthreads();
    // Q (waves 0-3) / K (waves 4-7): 4 tiles each
    {
      int sel = (wave >> 2);                 // 0=Q, 1=K
      int cb = (wave & 3) * 4;
      accfrag_t a4[4];
      wavegemm<8,4>(qkls, Wn + sel * 65536, 0, cb, a4);
      const float* bias = pb + sel * 1024 + ln * 256;
      unsigned short* C = QKV + (size_t)sel * BT * DD;
#pragma unroll
      for (int nt = 0; nt < 4; nt++) {
        int col = (cb + nt) * 16 + l16;
        float bv = bias[col];
#pragma unroll
        for (int r4 = 0; r4 < 4; r4++) {
          int row = rb * 16 + lq * 4 + r4;
          C[(size_t)row * DD + col] = f2b(a4[nt][r4] + bv);
        }
      }
    }
    // V: all 8 waves, 2 tiles each
    {
      accfrag_t a5[2];
      wavegemm<8,2>(xls, Wn + 2 * 65536, 0, wave * 2, a5);
      const float* bias = pb + 2 * 1024 + ln * 256;
      unsigned short* C = QKV + 2 * (size_t)BT * DD;
#pragma unroll
      for (int nt = 0; nt < 2; nt++) {
        int col = wave * 32 + nt * 16 + l16;
        float bv = bias[col];
#pragma unroll
        for (int r4 = 0; r4 < 4; r4++) {
          int row = rb * 16 + lq * 4 + r4;
          C[(size_t)row * DD + col] = f2b(a5[nt][r4] + bv);
        }
      }
    }
  }
}

// ---------------- launcher ----------------
extern "C" void kernel_launch(void* const* d_in, const int* in_sizes, int n_in,
                              void* d_out, int out_size, void* d_ws, size_t ws_size,
                              hipStream_t stream) {
  const void* map_tok   = d_in[0];
  const void* agent_tok = d_in[1];
  const void* light_tok = d_in[2];
  const void* map_pos   = d_in[3];
  const void* agent_pos = d_in[4];
  const void* light_pos = d_in[5];
  const void* Wq  = d_in[9];
  const void* bq  = d_in[10];
  const void* Wk  = d_in[11];
  const void* bk  = d_in[12];
  const void* Wv  = d_in[13];
  const void* bv  = d_in[14];
  const void* Wo  = d_in[15];
  const void* bo  = d_in[16];
  const void* W1  = d_in[17];
  const void* b1  = d_in[18];
  const void* W2  = d_in[19];
  const void* b2  = d_in[20];
  const void* ln1s = d_in[21];
  const void* ln1b = d_in[22];
  const void* ln2s = d_in[23];
  const void* ln2b = d_in[24];

  size_t off = 0;
  char* base = (char*)d_ws;
  auto take = [&](size_t bytes) { char* p = base + off; off += (bytes + 255) & ~(size_t)255; return (void*)p; };
  int*   flag  = (int*)take(256);
  float* posf  = (float*)take((size_t)BT * 2 * 4);
  float* pbuf  = (float*)take((size_t)FB_TOTAL * 4);
  unsigned short* pe_b = (unsigned short*)take((size_t)BT * DD * 2);
  float* out_f = (float*)take((size_t)BT * DD * 4);   // residual stream (f32)
  unsigned short* pk1  = (unsigned short*)take((size_t)BT * DD * 2);  // layer-0 x packed
  unsigned short* qkpk = (unsigned short*)take((size_t)BT * DD * 2);  // layer-0 x+pe packed
  unsigned short* QKV  = (unsigned short*)take((size_t)3 * BT * DD * 2);
  unsigned short* attnpk = (unsigned short*)take((size_t)BT * DD * 2);
  int* idxb = (int*)take((size_t)BT * KNN * 4);
  unsigned short* Wqkvpk = (unsigned short*)take((size_t)NLAYERS * 3 * DD * DD * 2);
  unsigned short* Wopk   = (unsigned short*)take((size_t)NLAYERS * DD * DD * 2);
  unsigned short* W1pk   = (unsigned short*)take((size_t)NLAYERS * DD * FFD * 2);
  unsigned short* W2pk   = (unsigned short*)take((size_t)NLAYERS * DD * FFD * 2);

  ParamSrc ps; ps.p[0]=bq; ps.p[1]=bk; ps.p[2]=bv; ps.p[3]=bo; ps.p[4]=b1;
  ps.p[5]=b2; ps.p[6]=ln1s; ps.p[7]=ln1b; ps.p[8]=ln2s; ps.p[9]=ln2b;
  ps.p[10]=map_pos; ps.p[11]=agent_pos; ps.p[12]=light_pos;
  conv_misc_kernel<<<BB + (FB_TOTAL + 255) / 256, 256, 0, stream>>>(ps, map_tok, flag, pbuf, posf);

  PackSrc pw; pw.s[0]=Wq; pw.s[1]=Wk; pw.s[2]=Wv; pw.s[3]=Wo; pw.s[4]=W1; pw.s[5]=W2;
  mega_kernel<<<21888, 256, 0, stream>>>(pw, map_tok, agent_tok, light_tok, posf, flag,
                                         Wqkvpk, Wopk, W1pk, W2pk,
                                         pe_b, out_f, pk1, qkpk, idxb);

  qkv_kernel<<<1440, 256, 0, stream>>>(qkpk, pk1, Wqkvpk, pbuf, 0, QKV);

  for (int l = 0; l < NLAYERS; l++) {
    attn_kernel<<<BT, 256, 0, stream>>>(QKV, idxb, attnpk);
    if (l < NLAYERS - 1)
      ffn_block_kernel<false><<<480, 512, 0, stream>>>(
          attnpk, Wopk + (size_t)l * 65536, W1pk + (size_t)l * 262144, W2pk + (size_t)l * 262144,
          Wqkvpk + (size_t)(l + 1) * 196608,
          pbuf + FB_BO + l * 256, pbuf + FB_B1 + l * 1024, pbuf + FB_B2 + l * 256,
          pbuf, l + 1,
          out_f, pe_b,
          pbuf + FB_LN1S + l * 256, pbuf + FB_LN1B + l * 256,
          pbuf + FB_LN2S + l * 256, pbuf + FB_LN2B + l * 256,
          QKV, d_out, flag);
    else
      ffn_block_kernel<true><<<480, 512, 0, stream>>>(
          attnpk, Wopk + (size_t)l * 65536, W1pk + (size_t)l * 262144, W2pk + (size_t)l * 262144,
          Wqkvpk,
          pbuf + FB_BO + l * 256, pbuf + FB_B1 + l * 1024, pbuf + FB_B2 + l * 256,
          pbuf, 0,
          out_f, pe_b,
          pbuf + FB_LN1S + l * 256, pbuf + FB_LN1B + l * 256,
          pbuf + FB_LN2S + l * 256, pbuf + FB_LN2B + l * 256,
          QKV, d_out, flag);
  }
}